// Round 2
// baseline (1054.627 us; speedup 1.0000x reference)
//
#include <hip/hip_runtime.h>
#include <hip/hip_bf16.h>

#define DIM 384
#define DI 768
#define S_LEN 1024
#define NB 32
#define M_ROWS (NB * S_LEN)   // 32768
#define MLP_DIM 1536

typedef __bf16 bf16x8 __attribute__((ext_vector_type(8)));
typedef float f32x4 __attribute__((ext_vector_type(4)));

// ---------------- LayerNorm: one wave per row of 384 ----------------
template <typename OutT>
__global__ __launch_bounds__(256) void ln_kernel(const float* __restrict__ x,
                                                 const float* __restrict__ gamma,
                                                 const float* __restrict__ beta,
                                                 OutT* __restrict__ out) {
    int row = blockIdx.x * 4 + (threadIdx.x >> 6);
    int lane = threadIdx.x & 63;
    const float* xr = x + (size_t)row * DIM;
    float v[6];
    float s = 0.f, sq = 0.f;
#pragma unroll
    for (int i = 0; i < 6; ++i) {
        v[i] = xr[lane + i * 64];
        s += v[i];
        sq += v[i] * v[i];
    }
#pragma unroll
    for (int off = 32; off > 0; off >>= 1) {
        s += __shfl_down(s, off);
        sq += __shfl_down(sq, off);
    }
    s = __shfl(s, 0);
    sq = __shfl(sq, 0);
    float mean = s * (1.f / DIM);
    float var = sq * (1.f / DIM) - mean * mean;
    float rstd = rsqrtf(var + 1e-5f);
    OutT* orow = out + (size_t)row * DIM;
#pragma unroll
    for (int i = 0; i < 6; ++i) {
        int c = lane + i * 64;
        float y = (v[i] - mean) * rstd * gamma[c] + beta[c];
        if constexpr (sizeof(OutT) == 2)
            orow[c] = __float2bfloat16(y);
        else
            orow[c] = y;
    }
}

// ---------------- Depthwise 3x3 conv (channel-last), +bias, -> bf16 ----------------
__global__ __launch_bounds__(256) void dwconv_kernel(const float* __restrict__ xn,
                                                     const float* __restrict__ w,
                                                     const float* __restrict__ b,
                                                     __hip_bfloat16* __restrict__ xs) {
    size_t idx = (size_t)blockIdx.x * 256 + threadIdx.x;  // over 32*1024*384
    int c = (int)(idx % DIM);
    int s = (int)((idx / DIM) % S_LEN);
    int n = (int)(idx / ((size_t)DIM * S_LEN));
    int h0 = s >> 5, w0 = s & 31;
    float acc = b[c];
#pragma unroll
    for (int kh = 0; kh < 3; ++kh) {
        int hh = h0 + kh - 1;
        if (hh < 0 || hh > 31) continue;
#pragma unroll
        for (int kw = 0; kw < 3; ++kw) {
            int ww = w0 + kw - 1;
            if (ww < 0 || ww > 31) continue;
            acc += xn[((size_t)n * S_LEN + hh * 32 + ww) * DIM + c] * w[c * 9 + kh * 3 + kw];
        }
    }
    xs[idx] = __float2bfloat16(acc);
}

// ---------------- transpose + cast f32 -> bf16: out[c*R + r] = in[r*C + c] ----------------
__global__ __launch_bounds__(256) void transpose_bf16_kernel(const float* __restrict__ in,
                                                             __hip_bfloat16* __restrict__ out,
                                                             int R, int C) {
    int idx = blockIdx.x * 256 + threadIdx.x;
    if (idx >= R * C) return;
    int r = idx / C, c = idx % C;
    out[(size_t)c * R + r] = __float2bfloat16(in[idx]);
}

// ---------------- minGRU scan: thread per (batch, channel) ----------------
__global__ __launch_bounds__(256) void scan_kernel(const __hip_bfloat16* __restrict__ hg,
                                                   __hip_bfloat16* __restrict__ h,
                                                   int rev) {
    int tid = blockIdx.x * 256 + threadIdx.x;  // 0..24575
    int b = tid / DI;
    int c = tid % DI;
    const __hip_bfloat16* base = hg + (size_t)b * S_LEN * (2 * DI);
    __hip_bfloat16* ho = h + (size_t)b * S_LEN * DI;
    float hp = 0.f;
    for (int i = 0; i < S_LEN; i += 8) {
        float hid[8], gate[8];
        int tt[8];
#pragma unroll
        for (int j = 0; j < 8; ++j) {
            int t = rev ? (S_LEN - 1 - (i + j)) : (i + j);
            tt[j] = t;
            hid[j] = __bfloat162float(base[(size_t)t * (2 * DI) + c]);
            gate[j] = __bfloat162float(base[(size_t)t * (2 * DI) + DI + c]);
        }
#pragma unroll
        for (int j = 0; j < 8; ++j) {
            float z = 1.f / (1.f + __expf(-gate[j]));
            float gh = (hid[j] >= 0.f) ? (hid[j] + 0.5f) : (1.f / (1.f + __expf(-hid[j])));
            hp = (1.f - z) * hp + z * gh;
            ho[(size_t)tt[j] * DI + c] = __float2bfloat16(hp);
        }
    }
}

// ---------------- bf16 MFMA GEMM, B pre-transposed (N x K) ----------------
// out = A(MxK) @ B(KxN) [+bias] [gelu] [+add], store bf16 (outH) or f32 (outF)
__global__ __launch_bounds__(256) void gemm_bt(const __hip_bfloat16* __restrict__ A,
                                               const __hip_bfloat16* __restrict__ Bt,
                                               int M, int N, int K,
                                               __hip_bfloat16* __restrict__ outH,
                                               float* __restrict__ outF,
                                               const float* __restrict__ bias,
                                               const float* __restrict__ add,
                                               int act) {
    __shared__ __align__(16) __hip_bfloat16 sA[128 * 40];  // 128 rows x (32+8 pad)
    __shared__ __align__(16) __hip_bfloat16 sB[128 * 40];
    int t = threadIdx.x;
    int n0 = blockIdx.x * 128;
    int m0 = blockIdx.y * 128;
    int wave = t >> 6, lane = t & 63;
    int wm = (wave >> 1) << 6, wn = (wave & 1) << 6;
    int quad = lane >> 4, lr = lane & 15;

    f32x4 acc[4][4];
#pragma unroll
    for (int i = 0; i < 4; ++i)
#pragma unroll
        for (int j = 0; j < 4; ++j)
#pragma unroll
            for (int e = 0; e < 4; ++e) acc[i][j][e] = 0.f;

    // staging: 128x32 = 4096 elems = 512 chunks of 8; thread handles chunks t and t+256
    int c0 = t, c1 = t + 256;
    int ar0 = c0 >> 2, ak0 = (c0 & 3) * 8;
    int ar1 = c1 >> 2, ak1 = (c1 & 3) * 8;

    const __hip_bfloat16* Ab = A + (size_t)m0 * K;
    const __hip_bfloat16* Bb = Bt + (size_t)n0 * K;

    for (int k0 = 0; k0 < K; k0 += 32) {
        *(int4*)&sA[ar0 * 40 + ak0] = *(const int4*)&Ab[(size_t)ar0 * K + k0 + ak0];
        *(int4*)&sA[ar1 * 40 + ak1] = *(const int4*)&Ab[(size_t)ar1 * K + k0 + ak1];
        *(int4*)&sB[ar0 * 40 + ak0] = *(const int4*)&Bb[(size_t)ar0 * K + k0 + ak0];
        *(int4*)&sB[ar1 * 40 + ak1] = *(const int4*)&Bb[(size_t)ar1 * K + k0 + ak1];
        __syncthreads();
        bf16x8 af[4], bf[4];
#pragma unroll
        for (int mi = 0; mi < 4; ++mi)
            af[mi] = *(const bf16x8*)&sA[(wm + mi * 16 + lr) * 40 + quad * 8];
#pragma unroll
        for (int ni = 0; ni < 4; ++ni)
            bf[ni] = *(const bf16x8*)&sB[(wn + ni * 16 + lr) * 40 + quad * 8];
#pragma unroll
        for (int mi = 0; mi < 4; ++mi)
#pragma unroll
            for (int ni = 0; ni < 4; ++ni)
                acc[mi][ni] = __builtin_amdgcn_mfma_f32_16x16x32_bf16(af[mi], bf[ni], acc[mi][ni], 0, 0, 0);
        __syncthreads();
    }

#pragma unroll
    for (int mi = 0; mi < 4; ++mi) {
#pragma unroll
        for (int ni = 0; ni < 4; ++ni) {
#pragma unroll
            for (int e = 0; e < 4; ++e) {
                int row = m0 + wm + mi * 16 + quad * 4 + e;
                int col = n0 + wn + ni * 16 + lr;
                size_t idx = (size_t)row * N + col;
                float v = acc[mi][ni][e];
                if (bias) v += bias[col];
                if (act == 1) v = 0.5f * v * (1.f + erff(v * 0.70710678118f));
                if (add) v += add[idx];
                if (outH)
                    outH[idx] = __float2bfloat16(v);
                else
                    outF[idx] = v;
            }
        }
    }
}

extern "C" void kernel_launch(void* const* d_in, const int* in_sizes, int n_in,
                              void* d_out, int out_size, void* d_ws, size_t ws_size,
                              hipStream_t stream) {
    const float* x = (const float*)d_in[0];
    const float* gamma1 = (const float*)d_in[1];
    const float* beta1 = (const float*)d_in[2];
    const float* dwc_w = (const float*)d_in[3];
    const float* dwc_b = (const float*)d_in[4];
    const float* gru1_w = (const float*)d_in[5];
    const float* gru1_o = (const float*)d_in[6];
    const float* gru2_w = (const float*)d_in[7];
    const float* gru2_o = (const float*)d_in[8];
    const float* gamma2 = (const float*)d_in[9];
    const float* beta2 = (const float*)d_in[10];
    const float* p1_w = (const float*)d_in[11];
    const float* p1_b = (const float*)d_in[12];
    const float* p2_w = (const float*)d_in[13];
    const float* p2_b = (const float*)d_in[14];
    float* out = (float*)d_out;

    char* ws = (char*)d_ws;
    size_t off = 0;
    auto alloc = [&](size_t b) {
        char* p = ws + off;
        off += (b + 255) & ~(size_t)255;
        return p;
    };
    const size_t M = M_ROWS;
    // ---- workspace (~183 MB total; was 309 MB -> suspected ws overflow) ----
    __hip_bfloat16* hg = (__hip_bfloat16*)alloc(M * 2 * DI * 2);   // 100.7 MB: gru gemm out; later t1
    __hip_bfloat16* hbuf = (__hip_bfloat16*)alloc(M * DI * 2);     // 50.3 MB: scan out
    __hip_bfloat16* xs = (__hip_bfloat16*)alloc(M * DIM * 2);      // 25.2 MB: conv out; later yn
    __hip_bfloat16* w1T = (__hip_bfloat16*)alloc((size_t)DIM * 2 * DI * 2);
    __hip_bfloat16* w2T = (__hip_bfloat16*)alloc((size_t)DIM * 2 * DI * 2);
    __hip_bfloat16* o1T = (__hip_bfloat16*)alloc((size_t)DI * DIM * 2);
    __hip_bfloat16* o2T = (__hip_bfloat16*)alloc((size_t)DI * DIM * 2);
    __hip_bfloat16* p1T = (__hip_bfloat16*)alloc((size_t)DIM * MLP_DIM * 2);
    __hip_bfloat16* p2T = (__hip_bfloat16*)alloc((size_t)MLP_DIM * DIM * 2);
    // ---- aliases (no extra ws) ----
    float* xn = (float*)d_out;            // LN1 out; dead after dwconv
    float* y = (float*)d_out;             // post-GRU residual; same-idx RMW only
    __hip_bfloat16* yn = xs;              // LN2 out; xs dead after GRU2 input GEMM
    __hip_bfloat16* t1 = hg;              // MLP hidden; hg dead after scan2

    // weight transposes (f32 -> bf16, row-major NxK)
    auto tgrid = [](int n) { return dim3((n + 255) / 256); };
    transpose_bf16_kernel<<<tgrid(DIM * 2 * DI), 256, 0, stream>>>(gru1_w, w1T, DIM, 2 * DI);
    transpose_bf16_kernel<<<tgrid(DIM * 2 * DI), 256, 0, stream>>>(gru2_w, w2T, DIM, 2 * DI);
    transpose_bf16_kernel<<<tgrid(DI * DIM), 256, 0, stream>>>(gru1_o, o1T, DI, DIM);
    transpose_bf16_kernel<<<tgrid(DI * DIM), 256, 0, stream>>>(gru2_o, o2T, DI, DIM);
    transpose_bf16_kernel<<<tgrid(DIM * MLP_DIM), 256, 0, stream>>>(p1_w, p1T, DIM, MLP_DIM);
    transpose_bf16_kernel<<<tgrid(MLP_DIM * DIM), 256, 0, stream>>>(p2_w, p2T, MLP_DIM, DIM);

    // LN1: x -> xn (= d_out)
    ln_kernel<float><<<dim3(M / 4), 256, 0, stream>>>(x, gamma1, beta1, xn);
    // depthwise conv: xn -> xs (bf16)
    dwconv_kernel<<<dim3((M * DIM) / 256), 256, 0, stream>>>(xn, dwc_w, dwc_b, xs);

    // GRU1: hg = xs @ gru1_w ; fwd scan ; y = h @ o1 + x
    gemm_bt<<<dim3(2 * DI / 128, M / 128), 256, 0, stream>>>(xs, w1T, M, 2 * DI, DIM, hg, nullptr, nullptr, nullptr, 0);
    scan_kernel<<<dim3(NB * DI / 256), 256, 0, stream>>>(hg, hbuf, 0);
    gemm_bt<<<dim3(DIM / 128, M / 128), 256, 0, stream>>>(hbuf, o1T, M, DIM, DI, nullptr, y, nullptr, x, 0);

    // GRU2: hg = xs @ gru2_w ; bwd scan ; y += h @ o2
    gemm_bt<<<dim3(2 * DI / 128, M / 128), 256, 0, stream>>>(xs, w2T, M, 2 * DI, DIM, hg, nullptr, nullptr, nullptr, 0);
    scan_kernel<<<dim3(NB * DI / 256), 256, 0, stream>>>(hg, hbuf, 1);
    gemm_bt<<<dim3(DIM / 128, M / 128), 256, 0, stream>>>(hbuf, o2T, M, DIM, DI, nullptr, y, nullptr, y, 0);

    // LN2: y -> yn (bf16, aliases xs)
    ln_kernel<__hip_bfloat16><<<dim3(M / 4), 256, 0, stream>>>(y, gamma2, beta2, yn);
    // MLP: t1 = gelu(yn @ p1 + b1) ; out = t1 @ p2 + b2 + y
    gemm_bt<<<dim3(MLP_DIM / 128, M / 128), 256, 0, stream>>>(yn, p1T, M, MLP_DIM, DIM, t1, nullptr, p1_b, nullptr, 1);
    gemm_bt<<<dim3(DIM / 128, M / 128), 256, 0, stream>>>(t1, p2T, M, DIM, MLP_DIM, nullptr, out, p2_b, y, 0);
}

// Round 3
// 929.115 us; speedup vs baseline: 1.1351x; 1.1351x over previous
//
#include <hip/hip_runtime.h>
#include <hip/hip_bf16.h>

#define DIM 384
#define DI 768
#define S_LEN 1024
#define NB 32
#define M_ROWS (NB * S_LEN)   // 32768
#define MLP_DIM 1536
#define CHUNKS 32
#define CLEN (S_LEN / CHUNKS)  // 32

typedef __bf16 bf16x8 __attribute__((ext_vector_type(8)));
typedef float f32x4 __attribute__((ext_vector_type(4)));

// ---------------- LayerNorm: one wave per row of 384 ----------------
template <typename OutT>
__global__ __launch_bounds__(256) void ln_kernel(const float* __restrict__ x,
                                                 const float* __restrict__ gamma,
                                                 const float* __restrict__ beta,
                                                 OutT* __restrict__ out) {
    int row = blockIdx.x * 4 + (threadIdx.x >> 6);
    int lane = threadIdx.x & 63;
    const float* xr = x + (size_t)row * DIM;
    float v[6];
    float s = 0.f, sq = 0.f;
#pragma unroll
    for (int i = 0; i < 6; ++i) {
        v[i] = xr[lane + i * 64];
        s += v[i];
        sq += v[i] * v[i];
    }
#pragma unroll
    for (int off = 32; off > 0; off >>= 1) {
        s += __shfl_down(s, off);
        sq += __shfl_down(sq, off);
    }
    s = __shfl(s, 0);
    sq = __shfl(sq, 0);
    float mean = s * (1.f / DIM);
    float var = sq * (1.f / DIM) - mean * mean;
    float rstd = rsqrtf(var + 1e-5f);
    OutT* orow = out + (size_t)row * DIM;
#pragma unroll
    for (int i = 0; i < 6; ++i) {
        int c = lane + i * 64;
        float y = (v[i] - mean) * rstd * gamma[c] + beta[c];
        if constexpr (sizeof(OutT) == 2)
            orow[c] = __float2bfloat16(y);
        else
            orow[c] = y;
    }
}

// ---------------- Depthwise 3x3 conv (channel-last), +bias, -> bf16 ----------------
__global__ __launch_bounds__(256) void dwconv_kernel(const float* __restrict__ xn,
                                                     const float* __restrict__ w,
                                                     const float* __restrict__ b,
                                                     __hip_bfloat16* __restrict__ xs) {
    size_t idx = (size_t)blockIdx.x * 256 + threadIdx.x;  // over 32*1024*384
    int c = (int)(idx % DIM);
    int s = (int)((idx / DIM) % S_LEN);
    int n = (int)(idx / ((size_t)DIM * S_LEN));
    int h0 = s >> 5, w0 = s & 31;
    float acc = b[c];
#pragma unroll
    for (int kh = 0; kh < 3; ++kh) {
        int hh = h0 + kh - 1;
        if (hh < 0 || hh > 31) continue;
#pragma unroll
        for (int kw = 0; kw < 3; ++kw) {
            int ww = w0 + kw - 1;
            if (ww < 0 || ww > 31) continue;
            acc += xn[((size_t)n * S_LEN + hh * 32 + ww) * DIM + c] * w[c * 9 + kh * 3 + kw];
        }
    }
    xs[idx] = __float2bfloat16(acc);
}

// ---------------- transpose + cast f32 -> bf16: out[c*R + r] = in[r*C + c] ----------------
__global__ __launch_bounds__(256) void transpose_bf16_kernel(const float* __restrict__ in,
                                                             __hip_bfloat16* __restrict__ out,
                                                             int R, int C) {
    int idx = blockIdx.x * 256 + threadIdx.x;
    if (idx >= R * C) return;
    int r = idx / C, c = idx % C;
    out[(size_t)c * R + r] = __float2bfloat16(in[idx]);
}

// ---------------- minGRU chunked scan ----------------
// linear recurrence h_t = a_t*h_{t-1} + b_t ; a=1-z, b=z*ghat
// part1: per (b, chunk, c): chunk summary A=prod(a), B=scan-from-0
__device__ __forceinline__ void gru_ab(float hid, float gate, float& a, float& bv) {
    float z = 1.f / (1.f + __expf(-gate));
    float gh = (hid >= 0.f) ? (hid + 0.5f) : (1.f / (1.f + __expf(-hid)));
    a = 1.f - z;
    bv = z * gh;
}

__global__ __launch_bounds__(256) void scan_part1(const __hip_bfloat16* __restrict__ hg,
                                                  float* __restrict__ summ, int rev) {
    int tid = blockIdx.x * 256 + threadIdx.x;  // NB*CHUNKS*DI
    int c = tid % DI;
    int j = (tid / DI) % CHUNKS;
    int b = tid / (DI * CHUNKS);
    const __hip_bfloat16* base = hg + (size_t)b * S_LEN * (2 * DI);
    float A = 1.f, Bv = 0.f;
    for (int i = 0; i < CLEN; i += 8) {
        float hid[8], gate[8];
#pragma unroll
        for (int q = 0; q < 8; ++q) {
            int pos = j * CLEN + i + q;
            int t = rev ? (S_LEN - 1 - pos) : pos;
            hid[q] = __bfloat162float(base[(size_t)t * (2 * DI) + c]);
            gate[q] = __bfloat162float(base[(size_t)t * (2 * DI) + DI + c]);
        }
#pragma unroll
        for (int q = 0; q < 8; ++q) {
            float a, bv;
            gru_ab(hid[q], gate[q], a, bv);
            A *= a;
            Bv = a * Bv + bv;
        }
    }
    int idx = (j * NB + b) * DI + c;  // plane [j][b][c] -> coalesced in c
    summ[idx] = A;
    summ[(size_t)CHUNKS * NB * DI + idx] = Bv;
}

// part2: combine preceding chunk summaries (L2-resident) for h_in, rescan chunk, write h
__global__ __launch_bounds__(256) void scan_part2(const __hip_bfloat16* __restrict__ hg,
                                                  const float* __restrict__ summ,
                                                  __hip_bfloat16* __restrict__ ho, int rev) {
    int tid = blockIdx.x * 256 + threadIdx.x;
    int c = tid % DI;
    int j = (tid / DI) % CHUNKS;  // uniform within a block (DI%256==0)
    int b = tid / (DI * CHUNKS);
    const float* sB = summ + (size_t)CHUNKS * NB * DI;
    float h = 0.f;
    for (int jp = 0; jp < j; ++jp) {
        int idx = (jp * NB + b) * DI + c;
        h = summ[idx] * h + sB[idx];
    }
    const __hip_bfloat16* base = hg + (size_t)b * S_LEN * (2 * DI);
    __hip_bfloat16* hob = ho + (size_t)b * S_LEN * DI;
    for (int i = 0; i < CLEN; i += 8) {
        float hid[8], gate[8];
        int tt[8];
#pragma unroll
        for (int q = 0; q < 8; ++q) {
            int pos = j * CLEN + i + q;
            int t = rev ? (S_LEN - 1 - pos) : pos;
            tt[q] = t;
            hid[q] = __bfloat162float(base[(size_t)t * (2 * DI) + c]);
            gate[q] = __bfloat162float(base[(size_t)t * (2 * DI) + DI + c]);
        }
#pragma unroll
        for (int q = 0; q < 8; ++q) {
            float a, bv;
            gru_ab(hid[q], gate[q], a, bv);
            h = a * h + bv;
            hob[(size_t)tt[q] * DI + c] = __float2bfloat16(h);
        }
    }
}

// ---------------- bf16 MFMA GEMM, B pre-transposed (N x K) ----------------
__global__ __launch_bounds__(256) void gemm_bt(const __hip_bfloat16* __restrict__ A,
                                               const __hip_bfloat16* __restrict__ Bt,
                                               int M, int N, int K,
                                               __hip_bfloat16* __restrict__ outH,
                                               float* __restrict__ outF,
                                               const float* __restrict__ bias,
                                               const float* __restrict__ add,
                                               int act) {
    __shared__ __align__(16) __hip_bfloat16 sA[128 * 40];
    __shared__ __align__(16) __hip_bfloat16 sB[128 * 40];
    int t = threadIdx.x;
    int n0 = blockIdx.x * 128;
    int m0 = blockIdx.y * 128;
    int wave = t >> 6, lane = t & 63;
    int wm = (wave >> 1) << 6, wn = (wave & 1) << 6;
    int quad = lane >> 4, lr = lane & 15;

    f32x4 acc[4][4];
#pragma unroll
    for (int i = 0; i < 4; ++i)
#pragma unroll
        for (int j = 0; j < 4; ++j)
#pragma unroll
            for (int e = 0; e < 4; ++e) acc[i][j][e] = 0.f;

    int c0 = t, c1 = t + 256;
    int ar0 = c0 >> 2, ak0 = (c0 & 3) * 8;
    int ar1 = c1 >> 2, ak1 = (c1 & 3) * 8;

    const __hip_bfloat16* Ab = A + (size_t)m0 * K;
    const __hip_bfloat16* Bb = Bt + (size_t)n0 * K;

    for (int k0 = 0; k0 < K; k0 += 32) {
        *(int4*)&sA[ar0 * 40 + ak0] = *(const int4*)&Ab[(size_t)ar0 * K + k0 + ak0];
        *(int4*)&sA[ar1 * 40 + ak1] = *(const int4*)&Ab[(size_t)ar1 * K + k0 + ak1];
        *(int4*)&sB[ar0 * 40 + ak0] = *(const int4*)&Bb[(size_t)ar0 * K + k0 + ak0];
        *(int4*)&sB[ar1 * 40 + ak1] = *(const int4*)&Bb[(size_t)ar1 * K + k0 + ak1];
        __syncthreads();
        bf16x8 af[4], bf[4];
#pragma unroll
        for (int mi = 0; mi < 4; ++mi)
            af[mi] = *(const bf16x8*)&sA[(wm + mi * 16 + lr) * 40 + quad * 8];
#pragma unroll
        for (int ni = 0; ni < 4; ++ni)
            bf[ni] = *(const bf16x8*)&sB[(wn + ni * 16 + lr) * 40 + quad * 8];
#pragma unroll
        for (int mi = 0; mi < 4; ++mi)
#pragma unroll
            for (int ni = 0; ni < 4; ++ni)
                acc[mi][ni] = __builtin_amdgcn_mfma_f32_16x16x32_bf16(af[mi], bf[ni], acc[mi][ni], 0, 0, 0);
        __syncthreads();
    }

#pragma unroll
    for (int mi = 0; mi < 4; ++mi) {
#pragma unroll
        for (int ni = 0; ni < 4; ++ni) {
#pragma unroll
            for (int e = 0; e < 4; ++e) {
                int row = m0 + wm + mi * 16 + quad * 4 + e;
                int col = n0 + wn + ni * 16 + lr;
                size_t idx = (size_t)row * N + col;
                float v = acc[mi][ni][e];
                if (bias) v += bias[col];
                if (act == 1) v = 0.5f * v * (1.f + erff(v * 0.70710678118f));
                if (add) v += add[idx];
                if (outH)
                    outH[idx] = __float2bfloat16(v);
                else
                    outF[idx] = v;
            }
        }
    }
}

extern "C" void kernel_launch(void* const* d_in, const int* in_sizes, int n_in,
                              void* d_out, int out_size, void* d_ws, size_t ws_size,
                              hipStream_t stream) {
    const float* x = (const float*)d_in[0];
    const float* gamma1 = (const float*)d_in[1];
    const float* beta1 = (const float*)d_in[2];
    const float* dwc_w = (const float*)d_in[3];
    const float* dwc_b = (const float*)d_in[4];
    const float* gru1_w = (const float*)d_in[5];
    const float* gru1_o = (const float*)d_in[6];
    const float* gru2_w = (const float*)d_in[7];
    const float* gru2_o = (const float*)d_in[8];
    const float* gamma2 = (const float*)d_in[9];
    const float* beta2 = (const float*)d_in[10];
    const float* p1_w = (const float*)d_in[11];
    const float* p1_b = (const float*)d_in[12];
    const float* p2_w = (const float*)d_in[13];
    const float* p2_b = (const float*)d_in[14];
    float* out = (float*)d_out;

    char* ws = (char*)d_ws;
    size_t off = 0;
    auto alloc = [&](size_t b) {
        char* p = ws + off;
        off += (b + 255) & ~(size_t)255;
        return p;
    };
    const size_t M = M_ROWS;
    __hip_bfloat16* hg = (__hip_bfloat16*)alloc(M * 2 * DI * 2);   // 100.7 MB; later t1
    __hip_bfloat16* hbuf = (__hip_bfloat16*)alloc(M * DI * 2);     // 50.3 MB
    __hip_bfloat16* xs = (__hip_bfloat16*)alloc(M * DIM * 2);      // 25.2 MB; later yn
    float* summ = (float*)alloc((size_t)2 * CHUNKS * NB * DI * 4); // 6.3 MB chunk summaries
    __hip_bfloat16* w1T = (__hip_bfloat16*)alloc((size_t)DIM * 2 * DI * 2);
    __hip_bfloat16* w2T = (__hip_bfloat16*)alloc((size_t)DIM * 2 * DI * 2);
    __hip_bfloat16* o1T = (__hip_bfloat16*)alloc((size_t)DI * DIM * 2);
    __hip_bfloat16* o2T = (__hip_bfloat16*)alloc((size_t)DI * DIM * 2);
    __hip_bfloat16* p1T = (__hip_bfloat16*)alloc((size_t)DIM * MLP_DIM * 2);
    __hip_bfloat16* p2T = (__hip_bfloat16*)alloc((size_t)MLP_DIM * DIM * 2);
    float* xn = (float*)d_out;
    float* y = (float*)d_out;
    __hip_bfloat16* yn = xs;
    __hip_bfloat16* t1 = hg;

    auto tgrid = [](int n) { return dim3((n + 255) / 256); };
    transpose_bf16_kernel<<<tgrid(DIM * 2 * DI), 256, 0, stream>>>(gru1_w, w1T, DIM, 2 * DI);
    transpose_bf16_kernel<<<tgrid(DIM * 2 * DI), 256, 0, stream>>>(gru2_w, w2T, DIM, 2 * DI);
    transpose_bf16_kernel<<<tgrid(DI * DIM), 256, 0, stream>>>(gru1_o, o1T, DI, DIM);
    transpose_bf16_kernel<<<tgrid(DI * DIM), 256, 0, stream>>>(gru2_o, o2T, DI, DIM);
    transpose_bf16_kernel<<<tgrid(DIM * MLP_DIM), 256, 0, stream>>>(p1_w, p1T, DIM, MLP_DIM);
    transpose_bf16_kernel<<<tgrid(MLP_DIM * DIM), 256, 0, stream>>>(p2_w, p2T, MLP_DIM, DIM);

    ln_kernel<float><<<dim3(M / 4), 256, 0, stream>>>(x, gamma1, beta1, xn);
    dwconv_kernel<<<dim3((M * DIM) / 256), 256, 0, stream>>>(xn, dwc_w, dwc_b, xs);

    const int scan_blocks = NB * CHUNKS * DI / 256;  // 3072
    // GRU1
    gemm_bt<<<dim3(2 * DI / 128, M / 128), 256, 0, stream>>>(xs, w1T, M, 2 * DI, DIM, hg, nullptr, nullptr, nullptr, 0);
    scan_part1<<<dim3(scan_blocks), 256, 0, stream>>>(hg, summ, 0);
    scan_part2<<<dim3(scan_blocks), 256, 0, stream>>>(hg, summ, hbuf, 0);
    gemm_bt<<<dim3(DIM / 128, M / 128), 256, 0, stream>>>(hbuf, o1T, M, DIM, DI, nullptr, y, nullptr, x, 0);

    // GRU2
    gemm_bt<<<dim3(2 * DI / 128, M / 128), 256, 0, stream>>>(xs, w2T, M, 2 * DI, DIM, hg, nullptr, nullptr, nullptr, 0);
    scan_part1<<<dim3(scan_blocks), 256, 0, stream>>>(hg, summ, 1);
    scan_part2<<<dim3(scan_blocks), 256, 0, stream>>>(hg, summ, hbuf, 1);
    gemm_bt<<<dim3(DIM / 128, M / 128), 256, 0, stream>>>(hbuf, o2T, M, DIM, DI, nullptr, y, nullptr, y, 0);

    // LN2 + MLP
    ln_kernel<__hip_bfloat16><<<dim3(M / 4), 256, 0, stream>>>(y, gamma2, beta2, yn);
    gemm_bt<<<dim3(MLP_DIM / 128, M / 128), 256, 0, stream>>>(yn, p1T, M, MLP_DIM, DIM, t1, nullptr, p1_b, nullptr, 1);
    gemm_bt<<<dim3(DIM / 128, M / 128), 256, 0, stream>>>(t1, p2T, M, DIM, MLP_DIM, nullptr, out, p2_b, y, 0);
}

// Round 4
// 917.677 us; speedup vs baseline: 1.1492x; 1.0125x over previous
//
#include <hip/hip_runtime.h>
#include <hip/hip_bf16.h>

#define DIM 384
#define DI 768
#define S_LEN 1024
#define NB 32
#define M_ROWS (NB * S_LEN)   // 32768
#define MLP_DIM 1536
#define CHUNKS 32
#define CLEN (S_LEN / CHUNKS)  // 32

typedef __bf16 bf16x8 __attribute__((ext_vector_type(8)));
typedef float f32x4 __attribute__((ext_vector_type(4)));

#define GLOBAL_AS __attribute__((address_space(1)))
#define LDS_AS __attribute__((address_space(3)))

// ---------------- LayerNorm: one wave per row of 384 ----------------
template <typename OutT>
__global__ __launch_bounds__(256) void ln_kernel(const float* __restrict__ x,
                                                 const float* __restrict__ gamma,
                                                 const float* __restrict__ beta,
                                                 OutT* __restrict__ out) {
    int row = blockIdx.x * 4 + (threadIdx.x >> 6);
    int lane = threadIdx.x & 63;
    const float* xr = x + (size_t)row * DIM;
    float v[6];
    float s = 0.f, sq = 0.f;
#pragma unroll
    for (int i = 0; i < 6; ++i) {
        v[i] = xr[lane + i * 64];
        s += v[i];
        sq += v[i] * v[i];
    }
#pragma unroll
    for (int off = 32; off > 0; off >>= 1) {
        s += __shfl_down(s, off);
        sq += __shfl_down(sq, off);
    }
    s = __shfl(s, 0);
    sq = __shfl(sq, 0);
    float mean = s * (1.f / DIM);
    float var = sq * (1.f / DIM) - mean * mean;
    float rstd = rsqrtf(var + 1e-5f);
    OutT* orow = out + (size_t)row * DIM;
#pragma unroll
    for (int i = 0; i < 6; ++i) {
        int c = lane + i * 64;
        float y = (v[i] - mean) * rstd * gamma[c] + beta[c];
        if constexpr (sizeof(OutT) == 2)
            orow[c] = __float2bfloat16(y);
        else
            orow[c] = y;
    }
}

// ---------------- Depthwise 3x3 conv (channel-last), +bias, -> bf16 ----------------
__global__ __launch_bounds__(256) void dwconv_kernel(const float* __restrict__ xn,
                                                     const float* __restrict__ w,
                                                     const float* __restrict__ b,
                                                     __hip_bfloat16* __restrict__ xs) {
    size_t idx = (size_t)blockIdx.x * 256 + threadIdx.x;  // over 32*1024*384
    int c = (int)(idx % DIM);
    int s = (int)((idx / DIM) % S_LEN);
    int n = (int)(idx / ((size_t)DIM * S_LEN));
    int h0 = s >> 5, w0 = s & 31;
    float acc = b[c];
#pragma unroll
    for (int kh = 0; kh < 3; ++kh) {
        int hh = h0 + kh - 1;
        if (hh < 0 || hh > 31) continue;
#pragma unroll
        for (int kw = 0; kw < 3; ++kw) {
            int ww = w0 + kw - 1;
            if (ww < 0 || ww > 31) continue;
            acc += xn[((size_t)n * S_LEN + hh * 32 + ww) * DIM + c] * w[c * 9 + kh * 3 + kw];
        }
    }
    xs[idx] = __float2bfloat16(acc);
}

// ---------------- transpose + cast f32 -> bf16: out[c*R + r] = in[r*C + c] ----------------
__global__ __launch_bounds__(256) void transpose_bf16_kernel(const float* __restrict__ in,
                                                             __hip_bfloat16* __restrict__ out,
                                                             int R, int C) {
    int idx = blockIdx.x * 256 + threadIdx.x;
    if (idx >= R * C) return;
    int r = idx / C, c = idx % C;
    out[(size_t)c * R + r] = __float2bfloat16(in[idx]);
}

// ---------------- minGRU chunked scan ----------------
__device__ __forceinline__ void gru_ab(float hid, float gate, float& a, float& bv) {
    float z = 1.f / (1.f + __expf(-gate));
    float gh = (hid >= 0.f) ? (hid + 0.5f) : (1.f / (1.f + __expf(-hid)));
    a = 1.f - z;
    bv = z * gh;
}

__global__ __launch_bounds__(256) void scan_part1(const __hip_bfloat16* __restrict__ hg,
                                                  float* __restrict__ summ, int rev) {
    int tid = blockIdx.x * 256 + threadIdx.x;  // NB*CHUNKS*DI
    int c = tid % DI;
    int j = (tid / DI) % CHUNKS;
    int b = tid / (DI * CHUNKS);
    const __hip_bfloat16* base = hg + (size_t)b * S_LEN * (2 * DI);
    float A = 1.f, Bv = 0.f;
    for (int i = 0; i < CLEN; i += 8) {
        float hid[8], gate[8];
#pragma unroll
        for (int q = 0; q < 8; ++q) {
            int pos = j * CLEN + i + q;
            int t = rev ? (S_LEN - 1 - pos) : pos;
            hid[q] = __bfloat162float(base[(size_t)t * (2 * DI) + c]);
            gate[q] = __bfloat162float(base[(size_t)t * (2 * DI) + DI + c]);
        }
#pragma unroll
        for (int q = 0; q < 8; ++q) {
            float a, bv;
            gru_ab(hid[q], gate[q], a, bv);
            A *= a;
            Bv = a * Bv + bv;
        }
    }
    int idx = (j * NB + b) * DI + c;
    summ[idx] = A;
    summ[(size_t)CHUNKS * NB * DI + idx] = Bv;
}

__global__ __launch_bounds__(256) void scan_part2(const __hip_bfloat16* __restrict__ hg,
                                                  const float* __restrict__ summ,
                                                  __hip_bfloat16* __restrict__ ho, int rev) {
    int tid = blockIdx.x * 256 + threadIdx.x;
    int c = tid % DI;
    int j = (tid / DI) % CHUNKS;
    int b = tid / (DI * CHUNKS);
    const float* sB = summ + (size_t)CHUNKS * NB * DI;
    float h = 0.f;
    for (int jp = 0; jp < j; ++jp) {
        int idx = (jp * NB + b) * DI + c;
        h = summ[idx] * h + sB[idx];
    }
    const __hip_bfloat16* base = hg + (size_t)b * S_LEN * (2 * DI);
    __hip_bfloat16* hob = ho + (size_t)b * S_LEN * DI;
    for (int i = 0; i < CLEN; i += 8) {
        float hid[8], gate[8];
        int tt[8];
#pragma unroll
        for (int q = 0; q < 8; ++q) {
            int pos = j * CLEN + i + q;
            int t = rev ? (S_LEN - 1 - pos) : pos;
            tt[q] = t;
            hid[q] = __bfloat162float(base[(size_t)t * (2 * DI) + c]);
            gate[q] = __bfloat162float(base[(size_t)t * (2 * DI) + DI + c]);
        }
#pragma unroll
        for (int q = 0; q < 8; ++q) {
            float a, bv;
            gru_ab(hid[q], gate[q], a, bv);
            h = a * h + bv;
            hob[(size_t)tt[q] * DI + c] = __float2bfloat16(h);
        }
    }
}

// ---------------- bf16 MFMA GEMM, m97-style global_load_lds staging ----------------
// out = A(MxK) @ B(KxN) [+bias] [gelu] [+add]; Bt is N x K; K % 32 == 0
__global__ __launch_bounds__(256) void gemm_bt(const __hip_bfloat16* __restrict__ A,
                                               const __hip_bfloat16* __restrict__ Bt,
                                               int M, int N, int K,
                                               __hip_bfloat16* __restrict__ outH,
                                               float* __restrict__ outF,
                                               const float* __restrict__ bias,
                                               const float* __restrict__ add,
                                               int act) {
    __shared__ __align__(16) __hip_bfloat16 sA[128 * 32];  // unpadded: global_load_lds layout
    __shared__ __align__(16) __hip_bfloat16 sB[128 * 32];
    int t = threadIdx.x;
    int n0 = blockIdx.x * 128;
    int m0 = blockIdx.y * 128;
    int wave = t >> 6, lane = t & 63;
    int wm = (wave >> 1) << 6, wn = (wave & 1) << 6;
    int quad = lane >> 4, lr = lane & 15;

    f32x4 acc[4][4];
#pragma unroll
    for (int i = 0; i < 4; ++i)
#pragma unroll
        for (int j = 0; j < 4; ++j)
#pragma unroll
            for (int e = 0; e < 4; ++e) acc[i][j][e] = 0.f;

    // staging: tile = 128x32 bf16 = 8192B = 512 chunks of 16B.
    // wave w covers chunks [w*128, w*128+128), two issues of 64 chunks.
    // chunk -> row = chunk>>2, colgrp = chunk&3 (8 elems); LDS dest = chunk*16B
    //   (wave-uniform base + lane*16 -- required layout for global_load_lds)
    int ch0 = wave * 128 + lane;        // issue 0
    int ch1 = wave * 128 + 64 + lane;   // issue 1
    int r0 = ch0 >> 2, g0 = (ch0 & 3) * 8;
    int r1 = ch1 >> 2, g1 = (ch1 & 3) * 8;

    const __hip_bfloat16* gA0 = A + (size_t)(m0 + r0) * K + g0;
    const __hip_bfloat16* gA1 = A + (size_t)(m0 + r1) * K + g1;
    const __hip_bfloat16* gB0 = Bt + (size_t)(n0 + r0) * K + g0;
    const __hip_bfloat16* gB1 = Bt + (size_t)(n0 + r1) * K + g1;
    LDS_AS __hip_bfloat16* lA0 = (LDS_AS __hip_bfloat16*)&sA[ch0 * 8];
    LDS_AS __hip_bfloat16* lA1 = (LDS_AS __hip_bfloat16*)&sA[ch1 * 8];
    LDS_AS __hip_bfloat16* lB0 = (LDS_AS __hip_bfloat16*)&sB[ch0 * 8];
    LDS_AS __hip_bfloat16* lB1 = (LDS_AS __hip_bfloat16*)&sB[ch1 * 8];

    for (int k0 = 0; k0 < K; k0 += 32) {
        __builtin_amdgcn_global_load_lds((const GLOBAL_AS void*)(gA0 + k0), (LDS_AS void*)lA0, 16, 0, 0);
        __builtin_amdgcn_global_load_lds((const GLOBAL_AS void*)(gA1 + k0), (LDS_AS void*)lA1, 16, 0, 0);
        __builtin_amdgcn_global_load_lds((const GLOBAL_AS void*)(gB0 + k0), (LDS_AS void*)lB0, 16, 0, 0);
        __builtin_amdgcn_global_load_lds((const GLOBAL_AS void*)(gB1 + k0), (LDS_AS void*)lB1, 16, 0, 0);
        __syncthreads();
        bf16x8 af[4], bfr[4];
#pragma unroll
        for (int mi = 0; mi < 4; ++mi)
            af[mi] = *(const bf16x8*)&sA[(wm + mi * 16 + lr) * 32 + quad * 8];
#pragma unroll
        for (int ni = 0; ni < 4; ++ni)
            bfr[ni] = *(const bf16x8*)&sB[(wn + ni * 16 + lr) * 32 + quad * 8];
#pragma unroll
        for (int mi = 0; mi < 4; ++mi)
#pragma unroll
            for (int ni = 0; ni < 4; ++ni)
                acc[mi][ni] = __builtin_amdgcn_mfma_f32_16x16x32_bf16(af[mi], bfr[ni], acc[mi][ni], 0, 0, 0);
        __syncthreads();
    }

#pragma unroll
    for (int mi = 0; mi < 4; ++mi) {
#pragma unroll
        for (int ni = 0; ni < 4; ++ni) {
#pragma unroll
            for (int e = 0; e < 4; ++e) {
                int row = m0 + wm + mi * 16 + quad * 4 + e;
                int col = n0 + wn + ni * 16 + lr;
                size_t idx = (size_t)row * N + col;
                float v = acc[mi][ni][e];
                if (bias) v += bias[col];
                if (act == 1) v = 0.5f * v * (1.f + erff(v * 0.70710678118f));
                if (add) v += add[idx];
                if (outH)
                    outH[idx] = __float2bfloat16(v);
                else
                    outF[idx] = v;
            }
        }
    }
}

extern "C" void kernel_launch(void* const* d_in, const int* in_sizes, int n_in,
                              void* d_out, int out_size, void* d_ws, size_t ws_size,
                              hipStream_t stream) {
    const float* x = (const float*)d_in[0];
    const float* gamma1 = (const float*)d_in[1];
    const float* beta1 = (const float*)d_in[2];
    const float* dwc_w = (const float*)d_in[3];
    const float* dwc_b = (const float*)d_in[4];
    const float* gru1_w = (const float*)d_in[5];
    const float* gru1_o = (const float*)d_in[6];
    const float* gru2_w = (const float*)d_in[7];
    const float* gru2_o = (const float*)d_in[8];
    const float* gamma2 = (const float*)d_in[9];
    const float* beta2 = (const float*)d_in[10];
    const float* p1_w = (const float*)d_in[11];
    const float* p1_b = (const float*)d_in[12];
    const float* p2_w = (const float*)d_in[13];
    const float* p2_b = (const float*)d_in[14];
    float* out = (float*)d_out;

    char* ws = (char*)d_ws;
    size_t off = 0;
    auto alloc = [&](size_t b) {
        char* p = ws + off;
        off += (b + 255) & ~(size_t)255;
        return p;
    };
    const size_t M = M_ROWS;
    __hip_bfloat16* hg = (__hip_bfloat16*)alloc(M * 2 * DI * 2);   // 100.7 MB; later t1
    __hip_bfloat16* hbuf = (__hip_bfloat16*)alloc(M * DI * 2);     // 50.3 MB
    __hip_bfloat16* xs = (__hip_bfloat16*)alloc(M * DIM * 2);      // 25.2 MB; later yn
    float* summ = (float*)alloc((size_t)2 * CHUNKS * NB * DI * 4); // 6.3 MB
    __hip_bfloat16* w1T = (__hip_bfloat16*)alloc((size_t)DIM * 2 * DI * 2);
    __hip_bfloat16* w2T = (__hip_bfloat16*)alloc((size_t)DIM * 2 * DI * 2);
    __hip_bfloat16* o1T = (__hip_bfloat16*)alloc((size_t)DI * DIM * 2);
    __hip_bfloat16* o2T = (__hip_bfloat16*)alloc((size_t)DI * DIM * 2);
    __hip_bfloat16* p1T = (__hip_bfloat16*)alloc((size_t)DIM * MLP_DIM * 2);
    __hip_bfloat16* p2T = (__hip_bfloat16*)alloc((size_t)MLP_DIM * DIM * 2);
    float* xn = (float*)d_out;
    float* y = (float*)d_out;
    __hip_bfloat16* yn = xs;
    __hip_bfloat16* t1 = hg;

    auto tgrid = [](int n) { return dim3((n + 255) / 256); };
    transpose_bf16_kernel<<<tgrid(DIM * 2 * DI), 256, 0, stream>>>(gru1_w, w1T, DIM, 2 * DI);
    transpose_bf16_kernel<<<tgrid(DIM * 2 * DI), 256, 0, stream>>>(gru2_w, w2T, DIM, 2 * DI);
    transpose_bf16_kernel<<<tgrid(DI * DIM), 256, 0, stream>>>(gru1_o, o1T, DI, DIM);
    transpose_bf16_kernel<<<tgrid(DI * DIM), 256, 0, stream>>>(gru2_o, o2T, DI, DIM);
    transpose_bf16_kernel<<<tgrid(DIM * MLP_DIM), 256, 0, stream>>>(p1_w, p1T, DIM, MLP_DIM);
    transpose_bf16_kernel<<<tgrid(MLP_DIM * DIM), 256, 0, stream>>>(p2_w, p2T, MLP_DIM, DIM);

    ln_kernel<float><<<dim3(M / 4), 256, 0, stream>>>(x, gamma1, beta1, xn);
    dwconv_kernel<<<dim3((M * DIM) / 256), 256, 0, stream>>>(xn, dwc_w, dwc_b, xs);

    const int scan_blocks = NB * CHUNKS * DI / 256;  // 3072
    // GRU1
    gemm_bt<<<dim3(2 * DI / 128, M / 128), 256, 0, stream>>>(xs, w1T, M, 2 * DI, DIM, hg, nullptr, nullptr, nullptr, 0);
    scan_part1<<<dim3(scan_blocks), 256, 0, stream>>>(hg, summ, 0);
    scan_part2<<<dim3(scan_blocks), 256, 0, stream>>>(hg, summ, hbuf, 0);
    gemm_bt<<<dim3(DIM / 128, M / 128), 256, 0, stream>>>(hbuf, o1T, M, DIM, DI, nullptr, y, nullptr, x, 0);

    // GRU2
    gemm_bt<<<dim3(2 * DI / 128, M / 128), 256, 0, stream>>>(xs, w2T, M, 2 * DI, DIM, hg, nullptr, nullptr, nullptr, 0);
    scan_part1<<<dim3(scan_blocks), 256, 0, stream>>>(hg, summ, 1);
    scan_part2<<<dim3(scan_blocks), 256, 0, stream>>>(hg, summ, hbuf, 1);
    gemm_bt<<<dim3(DIM / 128, M / 128), 256, 0, stream>>>(hbuf, o2T, M, DIM, DI, nullptr, y, nullptr, y, 0);

    // LN2 + MLP
    ln_kernel<__hip_bfloat16><<<dim3(M / 4), 256, 0, stream>>>(y, gamma2, beta2, yn);
    gemm_bt<<<dim3(MLP_DIM / 128, M / 128), 256, 0, stream>>>(yn, p1T, M, MLP_DIM, DIM, t1, nullptr, p1_b, nullptr, 1);
    gemm_bt<<<dim3(DIM / 128, M / 128), 256, 0, stream>>>(t1, p2T, M, DIM, MLP_DIM, nullptr, out, p2_b, y, 0);
}

// Round 5
// 898.269 us; speedup vs baseline: 1.1741x; 1.0216x over previous
//
#include <hip/hip_runtime.h>
#include <hip/hip_bf16.h>

#define DIM 384
#define DI 768
#define S_LEN 1024
#define NB 32
#define M_ROWS (NB * S_LEN)   // 32768
#define MLP_DIM 1536
#define CHUNKS 32
#define CLEN (S_LEN / CHUNKS)  // 32

typedef __bf16 bf16x8 __attribute__((ext_vector_type(8)));
typedef float f32x4 __attribute__((ext_vector_type(4)));

#define GLOBAL_AS __attribute__((address_space(1)))
#define LDS_AS __attribute__((address_space(3)))

// ---------------- LayerNorm: one wave per row of 384 ----------------
template <typename OutT>
__global__ __launch_bounds__(256) void ln_kernel(const float* __restrict__ x,
                                                 const float* __restrict__ gamma,
                                                 const float* __restrict__ beta,
                                                 OutT* __restrict__ out) {
    int row = blockIdx.x * 4 + (threadIdx.x >> 6);
    int lane = threadIdx.x & 63;
    const float* xr = x + (size_t)row * DIM;
    float v[6];
    float s = 0.f, sq = 0.f;
#pragma unroll
    for (int i = 0; i < 6; ++i) {
        v[i] = xr[lane + i * 64];
        s += v[i];
        sq += v[i] * v[i];
    }
#pragma unroll
    for (int off = 32; off > 0; off >>= 1) {
        s += __shfl_down(s, off);
        sq += __shfl_down(sq, off);
    }
    s = __shfl(s, 0);
    sq = __shfl(sq, 0);
    float mean = s * (1.f / DIM);
    float var = sq * (1.f / DIM) - mean * mean;
    float rstd = rsqrtf(var + 1e-5f);
    OutT* orow = out + (size_t)row * DIM;
#pragma unroll
    for (int i = 0; i < 6; ++i) {
        int c = lane + i * 64;
        float y = (v[i] - mean) * rstd * gamma[c] + beta[c];
        if constexpr (sizeof(OutT) == 2)
            orow[c] = __float2bfloat16(y);
        else
            orow[c] = y;
    }
}

// ---------------- Depthwise 3x3 conv (channel-last), +bias, -> bf16 ----------------
__global__ __launch_bounds__(256) void dwconv_kernel(const float* __restrict__ xn,
                                                     const float* __restrict__ w,
                                                     const float* __restrict__ b,
                                                     __hip_bfloat16* __restrict__ xs) {
    size_t idx = (size_t)blockIdx.x * 256 + threadIdx.x;  // over 32*1024*384
    int c = (int)(idx % DIM);
    int s = (int)((idx / DIM) % S_LEN);
    int n = (int)(idx / ((size_t)DIM * S_LEN));
    int h0 = s >> 5, w0 = s & 31;
    float acc = b[c];
#pragma unroll
    for (int kh = 0; kh < 3; ++kh) {
        int hh = h0 + kh - 1;
        if (hh < 0 || hh > 31) continue;
#pragma unroll
        for (int kw = 0; kw < 3; ++kw) {
            int ww = w0 + kw - 1;
            if (ww < 0 || ww > 31) continue;
            acc += xn[((size_t)n * S_LEN + hh * 32 + ww) * DIM + c] * w[c * 9 + kh * 3 + kw];
        }
    }
    xs[idx] = __float2bfloat16(acc);
}

// ---------------- transpose + cast f32 -> bf16: out[c*R + r] = in[r*C + c] ----------------
__global__ __launch_bounds__(256) void transpose_bf16_kernel(const float* __restrict__ in,
                                                             __hip_bfloat16* __restrict__ out,
                                                             int R, int C) {
    int idx = blockIdx.x * 256 + threadIdx.x;
    if (idx >= R * C) return;
    int r = idx / C, c = idx % C;
    out[(size_t)c * R + r] = __float2bfloat16(in[idx]);
}

// ---------------- minGRU chunked scan ----------------
__device__ __forceinline__ void gru_ab(float hid, float gate, float& a, float& bv) {
    float z = 1.f / (1.f + __expf(-gate));
    float gh = (hid >= 0.f) ? (hid + 0.5f) : (1.f / (1.f + __expf(-hid)));
    a = 1.f - z;
    bv = z * gh;
}

__global__ __launch_bounds__(256) void scan_part1(const __hip_bfloat16* __restrict__ hg,
                                                  float* __restrict__ summ, int rev) {
    int tid = blockIdx.x * 256 + threadIdx.x;  // NB*CHUNKS*DI
    int c = tid % DI;
    int j = (tid / DI) % CHUNKS;
    int b = tid / (DI * CHUNKS);
    const __hip_bfloat16* base = hg + (size_t)b * S_LEN * (2 * DI);
    float A = 1.f, Bv = 0.f;
    for (int i = 0; i < CLEN; i += 8) {
        float hid[8], gate[8];
#pragma unroll
        for (int q = 0; q < 8; ++q) {
            int pos = j * CLEN + i + q;
            int t = rev ? (S_LEN - 1 - pos) : pos;
            hid[q] = __bfloat162float(base[(size_t)t * (2 * DI) + c]);
            gate[q] = __bfloat162float(base[(size_t)t * (2 * DI) + DI + c]);
        }
#pragma unroll
        for (int q = 0; q < 8; ++q) {
            float a, bv;
            gru_ab(hid[q], gate[q], a, bv);
            A *= a;
            Bv = a * Bv + bv;
        }
    }
    int idx = (j * NB + b) * DI + c;
    summ[idx] = A;
    summ[(size_t)CHUNKS * NB * DI + idx] = Bv;
}

__global__ __launch_bounds__(256) void scan_part2(const __hip_bfloat16* __restrict__ hg,
                                                  const float* __restrict__ summ,
                                                  __hip_bfloat16* __restrict__ ho, int rev) {
    int tid = blockIdx.x * 256 + threadIdx.x;
    int c = tid % DI;
    int j = (tid / DI) % CHUNKS;
    int b = tid / (DI * CHUNKS);
    const float* sB = summ + (size_t)CHUNKS * NB * DI;
    float h = 0.f;
    for (int jp = 0; jp < j; ++jp) {
        int idx = (jp * NB + b) * DI + c;
        h = summ[idx] * h + sB[idx];
    }
    const __hip_bfloat16* base = hg + (size_t)b * S_LEN * (2 * DI);
    __hip_bfloat16* hob = ho + (size_t)b * S_LEN * DI;
    for (int i = 0; i < CLEN; i += 8) {
        float hid[8], gate[8];
        int tt[8];
#pragma unroll
        for (int q = 0; q < 8; ++q) {
            int pos = j * CLEN + i + q;
            int t = rev ? (S_LEN - 1 - pos) : pos;
            tt[q] = t;
            hid[q] = __bfloat162float(base[(size_t)t * (2 * DI) + c]);
            gate[q] = __bfloat162float(base[(size_t)t * (2 * DI) + DI + c]);
        }
#pragma unroll
        for (int q = 0; q < 8; ++q) {
            float a, bv;
            gru_ab(hid[q], gate[q], a, bv);
            h = a * h + bv;
            hob[(size_t)tt[q] * DI + c] = __float2bfloat16(h);
        }
    }
}

// ---------------- bf16 MFMA GEMM, global_load_lds staging, transposed-acc epilogue ----------------
// out = A(MxK) @ B(KxN) [+bias] [gelu] [+add]; Bt is N x K; K % 32 == 0
// MFMA called as (bfr, af): lane holds row m = base+lr (fixed), cols n = base+quad*4+e
// (4 consecutive) -> vectorized stores (dwordx2 bf16 / dwordx4 f32) instead of 64 scalar shorts.
__global__ __launch_bounds__(256) void gemm_bt(const __hip_bfloat16* __restrict__ A,
                                               const __hip_bfloat16* __restrict__ Bt,
                                               int M, int N, int K,
                                               __hip_bfloat16* __restrict__ outH,
                                               float* __restrict__ outF,
                                               const float* __restrict__ bias,
                                               const float* __restrict__ add,
                                               int act) {
    __shared__ __align__(16) __hip_bfloat16 sA[128 * 32];
    __shared__ __align__(16) __hip_bfloat16 sB[128 * 32];
    int t = threadIdx.x;
    int n0 = blockIdx.x * 128;
    int m0 = blockIdx.y * 128;
    int wave = t >> 6, lane = t & 63;
    int wm = (wave >> 1) << 6, wn = (wave & 1) << 6;
    int quad = lane >> 4, lr = lane & 15;

    f32x4 acc[4][4];
#pragma unroll
    for (int i = 0; i < 4; ++i)
#pragma unroll
        for (int j = 0; j < 4; ++j)
#pragma unroll
            for (int e = 0; e < 4; ++e) acc[i][j][e] = 0.f;

    int ch0 = wave * 128 + lane;
    int ch1 = wave * 128 + 64 + lane;
    int r0 = ch0 >> 2, g0 = (ch0 & 3) * 8;
    int r1 = ch1 >> 2, g1 = (ch1 & 3) * 8;

    const __hip_bfloat16* gA0 = A + (size_t)(m0 + r0) * K + g0;
    const __hip_bfloat16* gA1 = A + (size_t)(m0 + r1) * K + g1;
    const __hip_bfloat16* gB0 = Bt + (size_t)(n0 + r0) * K + g0;
    const __hip_bfloat16* gB1 = Bt + (size_t)(n0 + r1) * K + g1;
    LDS_AS __hip_bfloat16* lA0 = (LDS_AS __hip_bfloat16*)&sA[ch0 * 8];
    LDS_AS __hip_bfloat16* lA1 = (LDS_AS __hip_bfloat16*)&sA[ch1 * 8];
    LDS_AS __hip_bfloat16* lB0 = (LDS_AS __hip_bfloat16*)&sB[ch0 * 8];
    LDS_AS __hip_bfloat16* lB1 = (LDS_AS __hip_bfloat16*)&sB[ch1 * 8];

    for (int k0 = 0; k0 < K; k0 += 32) {
        __builtin_amdgcn_global_load_lds((const GLOBAL_AS void*)(gA0 + k0), (LDS_AS void*)lA0, 16, 0, 0);
        __builtin_amdgcn_global_load_lds((const GLOBAL_AS void*)(gA1 + k0), (LDS_AS void*)lA1, 16, 0, 0);
        __builtin_amdgcn_global_load_lds((const GLOBAL_AS void*)(gB0 + k0), (LDS_AS void*)lB0, 16, 0, 0);
        __builtin_amdgcn_global_load_lds((const GLOBAL_AS void*)(gB1 + k0), (LDS_AS void*)lB1, 16, 0, 0);
        __syncthreads();
        bf16x8 af[4], bfr[4];
#pragma unroll
        for (int mi = 0; mi < 4; ++mi)
            af[mi] = *(const bf16x8*)&sA[(wm + mi * 16 + lr) * 32 + quad * 8];
#pragma unroll
        for (int ni = 0; ni < 4; ++ni)
            bfr[ni] = *(const bf16x8*)&sB[(wn + ni * 16 + lr) * 32 + quad * 8];
#pragma unroll
        for (int mi = 0; mi < 4; ++mi)
#pragma unroll
            for (int ni = 0; ni < 4; ++ni)
                acc[mi][ni] = __builtin_amdgcn_mfma_f32_16x16x32_bf16(bfr[ni], af[mi], acc[mi][ni], 0, 0, 0);
        __syncthreads();
    }

    // epilogue: lane holds row = m0+wm+mi*16+lr, cols = n0+wn+ni*16+quad*4 .. +3
#pragma unroll
    for (int mi = 0; mi < 4; ++mi) {
        int row = m0 + wm + mi * 16 + lr;
#pragma unroll
        for (int ni = 0; ni < 4; ++ni) {
            int col = n0 + wn + ni * 16 + quad * 4;
            size_t idx = (size_t)row * N + col;
            f32x4 v = acc[mi][ni];
            if (bias) {
                const float4 b4 = *(const float4*)&bias[col];
                v[0] += b4.x; v[1] += b4.y; v[2] += b4.z; v[3] += b4.w;
            }
            if (act == 1) {
#pragma unroll
                for (int e = 0; e < 4; ++e)
                    v[e] = 0.5f * v[e] * (1.f + erff(v[e] * 0.70710678118f));
            }
            if (add) {
                const float4 a4 = *(const float4*)&add[idx];
                v[0] += a4.x; v[1] += a4.y; v[2] += a4.z; v[3] += a4.w;
            }
            if (outH) {
                union { __hip_bfloat16 h[4]; int2 i2; } u;
                u.h[0] = __float2bfloat16(v[0]);
                u.h[1] = __float2bfloat16(v[1]);
                u.h[2] = __float2bfloat16(v[2]);
                u.h[3] = __float2bfloat16(v[3]);
                *(int2*)&outH[idx] = u.i2;
            } else {
                float4 o4 = make_float4(v[0], v[1], v[2], v[3]);
                *(float4*)&outF[idx] = o4;
            }
        }
    }
}

extern "C" void kernel_launch(void* const* d_in, const int* in_sizes, int n_in,
                              void* d_out, int out_size, void* d_ws, size_t ws_size,
                              hipStream_t stream) {
    const float* x = (const float*)d_in[0];
    const float* gamma1 = (const float*)d_in[1];
    const float* beta1 = (const float*)d_in[2];
    const float* dwc_w = (const float*)d_in[3];
    const float* dwc_b = (const float*)d_in[4];
    const float* gru1_w = (const float*)d_in[5];
    const float* gru1_o = (const float*)d_in[6];
    const float* gru2_w = (const float*)d_in[7];
    const float* gru2_o = (const float*)d_in[8];
    const float* gamma2 = (const float*)d_in[9];
    const float* beta2 = (const float*)d_in[10];
    const float* p1_w = (const float*)d_in[11];
    const float* p1_b = (const float*)d_in[12];
    const float* p2_w = (const float*)d_in[13];
    const float* p2_b = (const float*)d_in[14];
    float* out = (float*)d_out;

    char* ws = (char*)d_ws;
    size_t off = 0;
    auto alloc = [&](size_t b) {
        char* p = ws + off;
        off += (b + 255) & ~(size_t)255;
        return p;
    };
    const size_t M = M_ROWS;
    __hip_bfloat16* hg = (__hip_bfloat16*)alloc(M * 2 * DI * 2);   // 100.7 MB; later t1
    __hip_bfloat16* hbuf = (__hip_bfloat16*)alloc(M * DI * 2);     // 50.3 MB
    __hip_bfloat16* xs = (__hip_bfloat16*)alloc(M * DIM * 2);      // 25.2 MB; later yn
    float* summ = (float*)alloc((size_t)2 * CHUNKS * NB * DI * 4); // 6.3 MB
    __hip_bfloat16* w1T = (__hip_bfloat16*)alloc((size_t)DIM * 2 * DI * 2);
    __hip_bfloat16* w2T = (__hip_bfloat16*)alloc((size_t)DIM * 2 * DI * 2);
    __hip_bfloat16* o1T = (__hip_bfloat16*)alloc((size_t)DI * DIM * 2);
    __hip_bfloat16* o2T = (__hip_bfloat16*)alloc((size_t)DI * DIM * 2);
    __hip_bfloat16* p1T = (__hip_bfloat16*)alloc((size_t)DIM * MLP_DIM * 2);
    __hip_bfloat16* p2T = (__hip_bfloat16*)alloc((size_t)MLP_DIM * DIM * 2);
    float* xn = (float*)d_out;
    float* y = (float*)d_out;
    __hip_bfloat16* yn = xs;
    __hip_bfloat16* t1 = hg;

    auto tgrid = [](int n) { return dim3((n + 255) / 256); };
    transpose_bf16_kernel<<<tgrid(DIM * 2 * DI), 256, 0, stream>>>(gru1_w, w1T, DIM, 2 * DI);
    transpose_bf16_kernel<<<tgrid(DIM * 2 * DI), 256, 0, stream>>>(gru2_w, w2T, DIM, 2 * DI);
    transpose_bf16_kernel<<<tgrid(DI * DIM), 256, 0, stream>>>(gru1_o, o1T, DI, DIM);
    transpose_bf16_kernel<<<tgrid(DI * DIM), 256, 0, stream>>>(gru2_o, o2T, DI, DIM);
    transpose_bf16_kernel<<<tgrid(DIM * MLP_DIM), 256, 0, stream>>>(p1_w, p1T, DIM, MLP_DIM);
    transpose_bf16_kernel<<<tgrid(MLP_DIM * DIM), 256, 0, stream>>>(p2_w, p2T, MLP_DIM, DIM);

    ln_kernel<float><<<dim3(M / 4), 256, 0, stream>>>(x, gamma1, beta1, xn);
    dwconv_kernel<<<dim3((M * DIM) / 256), 256, 0, stream>>>(xn, dwc_w, dwc_b, xs);

    const int scan_blocks = NB * CHUNKS * DI / 256;  // 3072
    // GRU1
    gemm_bt<<<dim3(2 * DI / 128, M / 128), 256, 0, stream>>>(xs, w1T, M, 2 * DI, DIM, hg, nullptr, nullptr, nullptr, 0);
    scan_part1<<<dim3(scan_blocks), 256, 0, stream>>>(hg, summ, 0);
    scan_part2<<<dim3(scan_blocks), 256, 0, stream>>>(hg, summ, hbuf, 0);
    gemm_bt<<<dim3(DIM / 128, M / 128), 256, 0, stream>>>(hbuf, o1T, M, DIM, DI, nullptr, y, nullptr, x, 0);

    // GRU2
    gemm_bt<<<dim3(2 * DI / 128, M / 128), 256, 0, stream>>>(xs, w2T, M, 2 * DI, DIM, hg, nullptr, nullptr, nullptr, 0);
    scan_part1<<<dim3(scan_blocks), 256, 0, stream>>>(hg, summ, 1);
    scan_part2<<<dim3(scan_blocks), 256, 0, stream>>>(hg, summ, hbuf, 1);
    gemm_bt<<<dim3(DIM / 128, M / 128), 256, 0, stream>>>(hbuf, o2T, M, DIM, DI, nullptr, y, nullptr, y, 0);

    // LN2 + MLP
    ln_kernel<__hip_bfloat16><<<dim3(M / 4), 256, 0, stream>>>(y, gamma2, beta2, yn);
    gemm_bt<<<dim3(MLP_DIM / 128, M / 128), 256, 0, stream>>>(yn, p1T, M, MLP_DIM, DIM, t1, nullptr, p1_b, nullptr, 1);
    gemm_bt<<<dim3(DIM / 128, M / 128), 256, 0, stream>>>(t1, p2T, M, DIM, MLP_DIM, nullptr, out, p2_b, y, 0);
}

// Round 6
// 889.620 us; speedup vs baseline: 1.1855x; 1.0097x over previous
//
#include <hip/hip_runtime.h>
#include <hip/hip_bf16.h>

#define DIM 384
#define DI 768
#define S_LEN 1024
#define NB 32
#define M_ROWS (NB * S_LEN)   // 32768
#define MLP_DIM 1536
#define CHUNKS 32
#define CLEN (S_LEN / CHUNKS)  // 32

typedef __bf16 bf16x8 __attribute__((ext_vector_type(8)));
typedef float f32x4 __attribute__((ext_vector_type(4)));
typedef int i32x2 __attribute__((ext_vector_type(2)));

#define GLOBAL_AS __attribute__((address_space(1)))
#define LDS_AS __attribute__((address_space(3)))

// ---------------- LayerNorm: one wave per row of 384 ----------------
template <typename OutT>
__global__ __launch_bounds__(256) void ln_kernel(const float* __restrict__ x,
                                                 const float* __restrict__ gamma,
                                                 const float* __restrict__ beta,
                                                 OutT* __restrict__ out) {
    int row = blockIdx.x * 4 + (threadIdx.x >> 6);
    int lane = threadIdx.x & 63;
    const float* xr = x + (size_t)row * DIM;
    float v[6];
    float s = 0.f, sq = 0.f;
#pragma unroll
    for (int i = 0; i < 6; ++i) {
        v[i] = xr[lane + i * 64];
        s += v[i];
        sq += v[i] * v[i];
    }
#pragma unroll
    for (int off = 32; off > 0; off >>= 1) {
        s += __shfl_down(s, off);
        sq += __shfl_down(sq, off);
    }
    s = __shfl(s, 0);
    sq = __shfl(sq, 0);
    float mean = s * (1.f / DIM);
    float var = sq * (1.f / DIM) - mean * mean;
    float rstd = rsqrtf(var + 1e-5f);
    OutT* orow = out + (size_t)row * DIM;
#pragma unroll
    for (int i = 0; i < 6; ++i) {
        int c = lane + i * 64;
        float y = (v[i] - mean) * rstd * gamma[c] + beta[c];
        if constexpr (sizeof(OutT) == 2)
            orow[c] = __float2bfloat16(y);
        else
            orow[c] = y;
    }
}

// ---------------- Depthwise 3x3 conv (channel-last), +bias, -> bf16 ----------------
__global__ __launch_bounds__(256) void dwconv_kernel(const float* __restrict__ xn,
                                                     const float* __restrict__ w,
                                                     const float* __restrict__ b,
                                                     __hip_bfloat16* __restrict__ xs) {
    size_t idx = (size_t)blockIdx.x * 256 + threadIdx.x;
    int c = (int)(idx % DIM);
    int s = (int)((idx / DIM) % S_LEN);
    int n = (int)(idx / ((size_t)DIM * S_LEN));
    int h0 = s >> 5, w0 = s & 31;
    float acc = b[c];
#pragma unroll
    for (int kh = 0; kh < 3; ++kh) {
        int hh = h0 + kh - 1;
        if (hh < 0 || hh > 31) continue;
#pragma unroll
        for (int kw = 0; kw < 3; ++kw) {
            int ww = w0 + kw - 1;
            if (ww < 0 || ww > 31) continue;
            acc += xn[((size_t)n * S_LEN + hh * 32 + ww) * DIM + c] * w[c * 9 + kh * 3 + kw];
        }
    }
    xs[idx] = __float2bfloat16(acc);
}

// ------------- transpose + cast f32 -> bf16: out[c*ostride + ooff + r] = in[r*C + c] -------------
__global__ __launch_bounds__(256) void transpose_bf16_kernel(const float* __restrict__ in,
                                                             __hip_bfloat16* __restrict__ out,
                                                             int R, int C, int ostride, int ooff) {
    int idx = blockIdx.x * 256 + threadIdx.x;
    if (idx >= R * C) return;
    int r = idx / C, c = idx % C;
    out[(size_t)c * ostride + ooff + r] = __float2bfloat16(in[idx]);
}

// ---------------- minGRU chunked scan ----------------
__device__ __forceinline__ void gru_ab(float hid, float gate, float& a, float& bv) {
    float z = 1.f / (1.f + __expf(-gate));
    float gh = (hid >= 0.f) ? (hid + 0.5f) : (1.f / (1.f + __expf(-hid)));
    a = 1.f - z;
    bv = z * gh;
}

__global__ __launch_bounds__(256) void scan_part1(const __hip_bfloat16* __restrict__ hg,
                                                  float* __restrict__ summ, int rev) {
    int tid = blockIdx.x * 256 + threadIdx.x;  // NB*CHUNKS*DI
    int c = tid % DI;
    int j = (tid / DI) % CHUNKS;
    int b = tid / (DI * CHUNKS);
    const __hip_bfloat16* base = hg + (size_t)b * S_LEN * (2 * DI);
    float A = 1.f, Bv = 0.f;
    for (int i = 0; i < CLEN; i += 8) {
        float hid[8], gate[8];
#pragma unroll
        for (int q = 0; q < 8; ++q) {
            int pos = j * CLEN + i + q;
            int t = rev ? (S_LEN - 1 - pos) : pos;
            hid[q] = __bfloat162float(base[(size_t)t * (2 * DI) + c]);
            gate[q] = __bfloat162float(base[(size_t)t * (2 * DI) + DI + c]);
        }
#pragma unroll
        for (int q = 0; q < 8; ++q) {
            float a, bv;
            gru_ab(hid[q], gate[q], a, bv);
            A *= a;
            Bv = a * Bv + bv;
        }
    }
    int idx = (j * NB + b) * DI + c;
    summ[idx] = A;
    summ[(size_t)CHUNKS * NB * DI + idx] = Bv;
}

// part2: writes h with row stride `ostride` (elements); may alias hg in-place
// (each thread reads hg[t][c]/hg[t][DI+c] before writing [t][c]; 1:1 addr map -> safe)
__global__ __launch_bounds__(256) void scan_part2(const __hip_bfloat16* __restrict__ hg,
                                                  const float* __restrict__ summ,
                                                  __hip_bfloat16* __restrict__ ho, int rev,
                                                  int ostride) {
    int tid = blockIdx.x * 256 + threadIdx.x;
    int c = tid % DI;
    int j = (tid / DI) % CHUNKS;
    int b = tid / (DI * CHUNKS);
    const float* sB = summ + (size_t)CHUNKS * NB * DI;
    float h = 0.f;
    for (int jp = 0; jp < j; ++jp) {
        int idx = (jp * NB + b) * DI + c;
        h = summ[idx] * h + sB[idx];
    }
    const __hip_bfloat16* base = hg + (size_t)b * S_LEN * (2 * DI);
    __hip_bfloat16* hob = ho + (size_t)b * S_LEN * ostride;
    for (int i = 0; i < CLEN; i += 8) {
        float hid[8], gate[8];
        int tt[8];
#pragma unroll
        for (int q = 0; q < 8; ++q) {
            int pos = j * CLEN + i + q;
            int t = rev ? (S_LEN - 1 - pos) : pos;
            tt[q] = t;
            hid[q] = __bfloat162float(base[(size_t)t * (2 * DI) + c]);
            gate[q] = __bfloat162float(base[(size_t)t * (2 * DI) + DI + c]);
        }
#pragma unroll
        for (int q = 0; q < 8; ++q) {
            float a, bv;
            gru_ab(hid[q], gate[q], a, bv);
            h = a * h + bv;
            hob[(size_t)tt[q] * ostride + c] = __float2bfloat16(h);
        }
    }
}

// ------- bf16 MFMA GEMM: dual-A (k-split), global_load_lds staging, nt-store epilogue -------
// out = [A1|A2](MxK) @ B(KxN); A1 rows lda1 covers k<ksplit, A2 rows lda2 covers k>=ksplit.
// Bt is N x K (stride K). MFMA as (b,a): lane -> row m (lr), 4 consecutive cols (quad).
__global__ __launch_bounds__(256) void gemm_bt(const __hip_bfloat16* __restrict__ A1, int lda1,
                                               const __hip_bfloat16* __restrict__ A2, int lda2,
                                               int ksplit,
                                               const __hip_bfloat16* __restrict__ Bt,
                                               int M, int N, int K,
                                               __hip_bfloat16* __restrict__ outH,
                                               float* __restrict__ outF,
                                               const float* __restrict__ bias,
                                               const float* __restrict__ add,
                                               int act) {
    __shared__ __align__(16) __hip_bfloat16 sA[128 * 32];
    __shared__ __align__(16) __hip_bfloat16 sB[128 * 32];
    int t = threadIdx.x;
    int n0 = blockIdx.x * 128;
    int m0 = blockIdx.y * 128;
    int wave = t >> 6, lane = t & 63;
    int wm = (wave >> 1) << 6, wn = (wave & 1) << 6;
    int quad = lane >> 4, lr = lane & 15;

    f32x4 acc[4][4];
#pragma unroll
    for (int i = 0; i < 4; ++i)
#pragma unroll
        for (int j = 0; j < 4; ++j)
#pragma unroll
            for (int e = 0; e < 4; ++e) acc[i][j][e] = 0.f;

    int ch0 = wave * 128 + lane;
    int ch1 = wave * 128 + 64 + lane;
    int r0 = ch0 >> 2, g0 = (ch0 & 3) * 8;
    int r1 = ch1 >> 2, g1 = (ch1 & 3) * 8;

    const __hip_bfloat16* gB0 = Bt + (size_t)(n0 + r0) * K + g0;
    const __hip_bfloat16* gB1 = Bt + (size_t)(n0 + r1) * K + g1;
    LDS_AS __hip_bfloat16* lA0 = (LDS_AS __hip_bfloat16*)&sA[ch0 * 8];
    LDS_AS __hip_bfloat16* lA1 = (LDS_AS __hip_bfloat16*)&sA[ch1 * 8];
    LDS_AS __hip_bfloat16* lB0 = (LDS_AS __hip_bfloat16*)&sB[ch0 * 8];
    LDS_AS __hip_bfloat16* lB1 = (LDS_AS __hip_bfloat16*)&sB[ch1 * 8];

    for (int k0 = 0; k0 < K; k0 += 32) {
        const __hip_bfloat16* Ab;
        int ldx, kk;
        if (k0 < ksplit) { Ab = A1; ldx = lda1; kk = k0; }
        else             { Ab = A2; ldx = lda2; kk = k0 - ksplit; }
        __builtin_amdgcn_global_load_lds((const GLOBAL_AS void*)(Ab + (size_t)(m0 + r0) * ldx + kk + g0),
                                         (LDS_AS void*)lA0, 16, 0, 0);
        __builtin_amdgcn_global_load_lds((const GLOBAL_AS void*)(Ab + (size_t)(m0 + r1) * ldx + kk + g1),
                                         (LDS_AS void*)lA1, 16, 0, 0);
        __builtin_amdgcn_global_load_lds((const GLOBAL_AS void*)(gB0 + k0), (LDS_AS void*)lB0, 16, 0, 0);
        __builtin_amdgcn_global_load_lds((const GLOBAL_AS void*)(gB1 + k0), (LDS_AS void*)lB1, 16, 0, 0);
        __syncthreads();
        bf16x8 af[4], bfr[4];
#pragma unroll
        for (int mi = 0; mi < 4; ++mi)
            af[mi] = *(const bf16x8*)&sA[(wm + mi * 16 + lr) * 32 + quad * 8];
#pragma unroll
        for (int ni = 0; ni < 4; ++ni)
            bfr[ni] = *(const bf16x8*)&sB[(wn + ni * 16 + lr) * 32 + quad * 8];
#pragma unroll
        for (int mi = 0; mi < 4; ++mi)
#pragma unroll
            for (int ni = 0; ni < 4; ++ni)
                acc[mi][ni] = __builtin_amdgcn_mfma_f32_16x16x32_bf16(bfr[ni], af[mi], acc[mi][ni], 0, 0, 0);
        __syncthreads();
    }

    // epilogue: row = m0+wm+mi*16+lr, cols = n0+wn+ni*16+quad*4 .. +3 ; nontemporal stores
#pragma unroll
    for (int mi = 0; mi < 4; ++mi) {
        int row = m0 + wm + mi * 16 + lr;
#pragma unroll
        for (int ni = 0; ni < 4; ++ni) {
            int col = n0 + wn + ni * 16 + quad * 4;
            size_t idx = (size_t)row * N + col;
            f32x4 v = acc[mi][ni];
            if (bias) {
                const float4 b4 = *(const float4*)&bias[col];
                v[0] += b4.x; v[1] += b4.y; v[2] += b4.z; v[3] += b4.w;
            }
            if (act == 1) {
#pragma unroll
                for (int e = 0; e < 4; ++e)
                    v[e] = 0.5f * v[e] * (1.f + erff(v[e] * 0.70710678118f));
            }
            if (add) {
                const float4 a4 = *(const float4*)&add[idx];
                v[0] += a4.x; v[1] += a4.y; v[2] += a4.z; v[3] += a4.w;
            }
            if (outH) {
                union { unsigned short h[4]; i32x2 w2; } u;
#pragma unroll
                for (int e = 0; e < 4; ++e) {
                    union { __hip_bfloat16 b; unsigned short us; } cv;
                    cv.b = __float2bfloat16(v[e]);
                    u.h[e] = cv.us;
                }
                __builtin_nontemporal_store(u.w2, (i32x2*)&outH[idx]);
            } else {
                __builtin_nontemporal_store(v, (f32x4*)&outF[idx]);
            }
        }
    }
}

extern "C" void kernel_launch(void* const* d_in, const int* in_sizes, int n_in,
                              void* d_out, int out_size, void* d_ws, size_t ws_size,
                              hipStream_t stream) {
    const float* x = (const float*)d_in[0];
    const float* gamma1 = (const float*)d_in[1];
    const float* beta1 = (const float*)d_in[2];
    const float* dwc_w = (const float*)d_in[3];
    const float* dwc_b = (const float*)d_in[4];
    const float* gru1_w = (const float*)d_in[5];
    const float* gru1_o = (const float*)d_in[6];
    const float* gru2_w = (const float*)d_in[7];
    const float* gru2_o = (const float*)d_in[8];
    const float* gamma2 = (const float*)d_in[9];
    const float* beta2 = (const float*)d_in[10];
    const float* p1_w = (const float*)d_in[11];
    const float* p1_b = (const float*)d_in[12];
    const float* p2_w = (const float*)d_in[13];
    const float* p2_b = (const float*)d_in[14];
    float* out = (float*)d_out;

    char* ws = (char*)d_ws;
    size_t off = 0;
    auto alloc = [&](size_t b) {
        char* p = ws + off;
        off += (b + 255) & ~(size_t)255;
        return p;
    };
    const size_t M = M_ROWS;
    // ws total ~188 MB
    __hip_bfloat16* hg = (__hip_bfloat16*)alloc(M * 2 * DI * 2);    // 100.7 MB; h2 in-place; later t1
    __hip_bfloat16* hbuf = (__hip_bfloat16*)alloc(M * DI * 2);      // 50.3 MB: h1
    __hip_bfloat16* xs = (__hip_bfloat16*)alloc(M * DIM * 2);       // 25.2 MB; later yn
    float* summ = (float*)alloc((size_t)2 * CHUNKS * NB * DI * 4);  // 6.3 MB
    __hip_bfloat16* w1T = (__hip_bfloat16*)alloc((size_t)DIM * 2 * DI * 2);
    __hip_bfloat16* w2T = (__hip_bfloat16*)alloc((size_t)DIM * 2 * DI * 2);
    __hip_bfloat16* ocT = (__hip_bfloat16*)alloc((size_t)DIM * 2 * DI * 2);  // 384 x 1536 = [o1;o2]^T
    __hip_bfloat16* p1T = (__hip_bfloat16*)alloc((size_t)DIM * MLP_DIM * 2);
    __hip_bfloat16* p2T = (__hip_bfloat16*)alloc((size_t)MLP_DIM * DIM * 2);
    float* xn = (float*)d_out;
    float* y = (float*)d_out;
    __hip_bfloat16* yn = xs;
    __hip_bfloat16* t1 = hg;

    auto tgrid = [](int n) { return dim3((n + 255) / 256); };
    transpose_bf16_kernel<<<tgrid(DIM * 2 * DI), 256, 0, stream>>>(gru1_w, w1T, DIM, 2 * DI, DIM, 0);
    transpose_bf16_kernel<<<tgrid(DIM * 2 * DI), 256, 0, stream>>>(gru2_w, w2T, DIM, 2 * DI, DIM, 0);
    transpose_bf16_kernel<<<tgrid(DI * DIM), 256, 0, stream>>>(gru1_o, ocT, DI, DIM, 2 * DI, 0);
    transpose_bf16_kernel<<<tgrid(DI * DIM), 256, 0, stream>>>(gru2_o, ocT, DI, DIM, 2 * DI, DI);
    transpose_bf16_kernel<<<tgrid(DIM * MLP_DIM), 256, 0, stream>>>(p1_w, p1T, DIM, MLP_DIM, DIM, 0);
    transpose_bf16_kernel<<<tgrid(MLP_DIM * DIM), 256, 0, stream>>>(p2_w, p2T, MLP_DIM, DIM, MLP_DIM, 0);

    ln_kernel<float><<<dim3(M / 4), 256, 0, stream>>>(x, gamma1, beta1, xn);
    dwconv_kernel<<<dim3((M * DIM) / 256), 256, 0, stream>>>(xn, dwc_w, dwc_b, xs);

    const int scan_blocks = NB * CHUNKS * DI / 256;  // 3072
    // GRU1: hg = xs @ w1; scan fwd -> h1 (hbuf, stride DI)
    gemm_bt<<<dim3(2 * DI / 128, M / 128), 256, 0, stream>>>(xs, DIM, xs, DIM, DIM, w1T, M, 2 * DI, DIM,
                                                             hg, nullptr, nullptr, nullptr, 0);
    scan_part1<<<dim3(scan_blocks), 256, 0, stream>>>(hg, summ, 0);
    scan_part2<<<dim3(scan_blocks), 256, 0, stream>>>(hg, summ, hbuf, 0, DI);
    // GRU2: hg = xs @ w2; scan bwd -> h2 written in-place into hg[:, 0:DI] (stride 2*DI)
    gemm_bt<<<dim3(2 * DI / 128, M / 128), 256, 0, stream>>>(xs, DIM, xs, DIM, DIM, w2T, M, 2 * DI, DIM,
                                                             hg, nullptr, nullptr, nullptr, 0);
    scan_part1<<<dim3(scan_blocks), 256, 0, stream>>>(hg, summ, 1);
    scan_part2<<<dim3(scan_blocks), 256, 0, stream>>>(hg, summ, hg, 1, 2 * DI);

    // merged GRU out: y = [h1 | h2] @ [o1;o2] + x   (K=1536, A1=hbuf lda=DI, A2=hg lda=2*DI)
    gemm_bt<<<dim3(DIM / 128, M / 128), 256, 0, stream>>>(hbuf, DI, hg, 2 * DI, DI, ocT, M, DIM, 2 * DI,
                                                          nullptr, y, nullptr, x, 0);

    // LN2 + MLP
    ln_kernel<__hip_bfloat16><<<dim3(M / 4), 256, 0, stream>>>(y, gamma2, beta2, yn);
    gemm_bt<<<dim3(MLP_DIM / 128, M / 128), 256, 0, stream>>>(yn, DIM, yn, DIM, DIM, p1T, M, MLP_DIM, DIM,
                                                              t1, nullptr, p1_b, nullptr, 1);
    gemm_bt<<<dim3(DIM / 128, M / 128), 256, 0, stream>>>(t1, MLP_DIM, t1, MLP_DIM, MLP_DIM, p2T, M, DIM, MLP_DIM,
                                                          nullptr, out, p2_b, y, 0);
}

// Round 7
// 822.283 us; speedup vs baseline: 1.2826x; 1.0819x over previous
//
#include <hip/hip_runtime.h>
#include <hip/hip_bf16.h>

#define DIM 384
#define DI 768
#define S_LEN 1024
#define NB 32
#define M_ROWS (NB * S_LEN)   // 32768
#define MLP_DIM 1536
#define CHUNKS 32
#define CLEN (S_LEN / CHUNKS)  // 32

typedef __bf16 bf16x8 __attribute__((ext_vector_type(8)));
typedef float f32x4 __attribute__((ext_vector_type(4)));

#define GLOBAL_AS __attribute__((address_space(1)))
#define LDS_AS __attribute__((address_space(3)))

// ---------------- LayerNorm: one wave per row of 384 ----------------
template <typename OutT>
__global__ __launch_bounds__(256) void ln_kernel(const float* __restrict__ x,
                                                 const float* __restrict__ gamma,
                                                 const float* __restrict__ beta,
                                                 OutT* __restrict__ out) {
    int row = blockIdx.x * 4 + (threadIdx.x >> 6);
    int lane = threadIdx.x & 63;
    const float* xr = x + (size_t)row * DIM;
    float v[6];
    float s = 0.f, sq = 0.f;
#pragma unroll
    for (int i = 0; i < 6; ++i) {
        v[i] = xr[lane + i * 64];
        s += v[i];
        sq += v[i] * v[i];
    }
#pragma unroll
    for (int off = 32; off > 0; off >>= 1) {
        s += __shfl_down(s, off);
        sq += __shfl_down(sq, off);
    }
    s = __shfl(s, 0);
    sq = __shfl(sq, 0);
    float mean = s * (1.f / DIM);
    float var = sq * (1.f / DIM) - mean * mean;
    float rstd = rsqrtf(var + 1e-5f);
    OutT* orow = out + (size_t)row * DIM;
#pragma unroll
    for (int i = 0; i < 6; ++i) {
        int c = lane + i * 64;
        float y = (v[i] - mean) * rstd * gamma[c] + beta[c];
        if constexpr (sizeof(OutT) == 2)
            orow[c] = __float2bfloat16(y);
        else
            orow[c] = y;
    }
}

// ---------------- Depthwise 3x3 conv (channel-last, bf16 in), +bias, -> bf16 ----------------
__global__ __launch_bounds__(256) void dwconv_kernel(const __hip_bfloat16* __restrict__ xn,
                                                     const float* __restrict__ w,
                                                     const float* __restrict__ b,
                                                     __hip_bfloat16* __restrict__ xs) {
    size_t idx = (size_t)blockIdx.x * 256 + threadIdx.x;
    int c = (int)(idx % DIM);
    int s = (int)((idx / DIM) % S_LEN);
    int n = (int)(idx / ((size_t)DIM * S_LEN));
    int h0 = s >> 5, w0 = s & 31;
    float acc = b[c];
#pragma unroll
    for (int kh = 0; kh < 3; ++kh) {
        int hh = h0 + kh - 1;
        if (hh < 0 || hh > 31) continue;
#pragma unroll
        for (int kw = 0; kw < 3; ++kw) {
            int ww = w0 + kw - 1;
            if (ww < 0 || ww > 31) continue;
            acc += __bfloat162float(xn[((size_t)n * S_LEN + hh * 32 + ww) * DIM + c]) * w[c * 9 + kh * 3 + kw];
        }
    }
    xs[idx] = __float2bfloat16(acc);
}

// ------------- transpose + cast f32 -> bf16: out[c*ostride + ooff + r] = in[r*C + c] -------------
__global__ __launch_bounds__(256) void transpose_bf16_kernel(const float* __restrict__ in,
                                                             __hip_bfloat16* __restrict__ out,
                                                             int R, int C, int ostride, int ooff) {
    int idx = blockIdx.x * 256 + threadIdx.x;
    if (idx >= R * C) return;
    int r = idx / C, c = idx % C;
    out[(size_t)c * ostride + ooff + r] = __float2bfloat16(in[idx]);
}

// ---------------- minGRU chunked scan ----------------
__device__ __forceinline__ void gru_ab(float hid, float gate, float& a, float& bv) {
    float z = 1.f / (1.f + __expf(-gate));
    float gh = (hid >= 0.f) ? (hid + 0.5f) : (1.f / (1.f + __expf(-hid)));
    a = 1.f - z;
    bv = z * gh;
}

__global__ __launch_bounds__(256) void scan_part1(const __hip_bfloat16* __restrict__ hg,
                                                  float* __restrict__ summ, int rev) {
    int tid = blockIdx.x * 256 + threadIdx.x;  // NB*CHUNKS*DI
    int c = tid % DI;
    int j = (tid / DI) % CHUNKS;
    int b = tid / (DI * CHUNKS);
    const __hip_bfloat16* base = hg + (size_t)b * S_LEN * (2 * DI);
    float A = 1.f, Bv = 0.f;
    for (int i = 0; i < CLEN; i += 8) {
        float hid[8], gate[8];
#pragma unroll
        for (int q = 0; q < 8; ++q) {
            int pos = j * CLEN + i + q;
            int t = rev ? (S_LEN - 1 - pos) : pos;
            hid[q] = __bfloat162float(base[(size_t)t * (2 * DI) + c]);
            gate[q] = __bfloat162float(base[(size_t)t * (2 * DI) + DI + c]);
        }
#pragma unroll
        for (int q = 0; q < 8; ++q) {
            float a, bv;
            gru_ab(hid[q], gate[q], a, bv);
            A *= a;
            Bv = a * Bv + bv;
        }
    }
    int idx = (j * NB + b) * DI + c;
    summ[idx] = A;
    summ[(size_t)CHUNKS * NB * DI + idx] = Bv;
}

// part2: writes h with row stride `ostride`; may alias hg in-place (1:1 read-before-write)
__global__ __launch_bounds__(256) void scan_part2(const __hip_bfloat16* __restrict__ hg,
                                                  const float* __restrict__ summ,
                                                  __hip_bfloat16* __restrict__ ho, int rev,
                                                  int ostride) {
    int tid = blockIdx.x * 256 + threadIdx.x;
    int c = tid % DI;
    int j = (tid / DI) % CHUNKS;
    int b = tid / (DI * CHUNKS);
    const float* sB = summ + (size_t)CHUNKS * NB * DI;
    float h = 0.f;
    for (int jp = 0; jp < j; ++jp) {
        int idx = (jp * NB + b) * DI + c;
        h = summ[idx] * h + sB[idx];
    }
    const __hip_bfloat16* base = hg + (size_t)b * S_LEN * (2 * DI);
    __hip_bfloat16* hob = ho + (size_t)b * S_LEN * ostride;
    for (int i = 0; i < CLEN; i += 8) {
        float hid[8], gate[8];
        int tt[8];
#pragma unroll
        for (int q = 0; q < 8; ++q) {
            int pos = j * CLEN + i + q;
            int t = rev ? (S_LEN - 1 - pos) : pos;
            tt[q] = t;
            hid[q] = __bfloat162float(base[(size_t)t * (2 * DI) + c]);
            gate[q] = __bfloat162float(base[(size_t)t * (2 * DI) + DI + c]);
        }
#pragma unroll
        for (int q = 0; q < 8; ++q) {
            float a, bv;
            gru_ab(hid[q], gate[q], a, bv);
            h = a * h + bv;
            hob[(size_t)tt[q] * ostride + c] = __float2bfloat16(h);
        }
    }
}

// ------- bf16 MFMA GEMM: dual-A (k-split), global_load_lds staging, vectorized epilogue -------
// out = [A1|A2](MxK) @ B(KxN); Bt is N x K. MFMA as (b,a): lane -> row m (lr), 4 consecutive cols.
__global__ __launch_bounds__(256) void gemm_bt(const __hip_bfloat16* __restrict__ A1, int lda1,
                                               const __hip_bfloat16* __restrict__ A2, int lda2,
                                               int ksplit,
                                               const __hip_bfloat16* __restrict__ Bt,
                                               int M, int N, int K,
                                               __hip_bfloat16* __restrict__ outH,
                                               float* __restrict__ outF,
                                               const float* __restrict__ bias,
                                               const float* __restrict__ add,
                                               int act) {
    __shared__ __align__(16) __hip_bfloat16 sA[128 * 32];
    __shared__ __align__(16) __hip_bfloat16 sB[128 * 32];
    int t = threadIdx.x;
    int n0 = blockIdx.x * 128;
    int m0 = blockIdx.y * 128;
    int wave = t >> 6, lane = t & 63;
    int wm = (wave >> 1) << 6, wn = (wave & 1) << 6;
    int quad = lane >> 4, lr = lane & 15;

    f32x4 acc[4][4];
#pragma unroll
    for (int i = 0; i < 4; ++i)
#pragma unroll
        for (int j = 0; j < 4; ++j)
#pragma unroll
            for (int e = 0; e < 4; ++e) acc[i][j][e] = 0.f;

    int ch0 = wave * 128 + lane;
    int ch1 = wave * 128 + 64 + lane;
    int r0 = ch0 >> 2, g0 = (ch0 & 3) * 8;
    int r1 = ch1 >> 2, g1 = (ch1 & 3) * 8;

    const __hip_bfloat16* gB0 = Bt + (size_t)(n0 + r0) * K + g0;
    const __hip_bfloat16* gB1 = Bt + (size_t)(n0 + r1) * K + g1;
    LDS_AS __hip_bfloat16* lA0 = (LDS_AS __hip_bfloat16*)&sA[ch0 * 8];
    LDS_AS __hip_bfloat16* lA1 = (LDS_AS __hip_bfloat16*)&sA[ch1 * 8];
    LDS_AS __hip_bfloat16* lB0 = (LDS_AS __hip_bfloat16*)&sB[ch0 * 8];
    LDS_AS __hip_bfloat16* lB1 = (LDS_AS __hip_bfloat16*)&sB[ch1 * 8];

    for (int k0 = 0; k0 < K; k0 += 32) {
        const __hip_bfloat16* Ab;
        int ldx, kk;
        if (k0 < ksplit) { Ab = A1; ldx = lda1; kk = k0; }
        else             { Ab = A2; ldx = lda2; kk = k0 - ksplit; }
        __builtin_amdgcn_global_load_lds((const GLOBAL_AS void*)(Ab + (size_t)(m0 + r0) * ldx + kk + g0),
                                         (LDS_AS void*)lA0, 16, 0, 0);
        __builtin_amdgcn_global_load_lds((const GLOBAL_AS void*)(Ab + (size_t)(m0 + r1) * ldx + kk + g1),
                                         (LDS_AS void*)lA1, 16, 0, 0);
        __builtin_amdgcn_global_load_lds((const GLOBAL_AS void*)(gB0 + k0), (LDS_AS void*)lB0, 16, 0, 0);
        __builtin_amdgcn_global_load_lds((const GLOBAL_AS void*)(gB1 + k0), (LDS_AS void*)lB1, 16, 0, 0);
        __syncthreads();
        bf16x8 af[4], bfr[4];
#pragma unroll
        for (int mi = 0; mi < 4; ++mi)
            af[mi] = *(const bf16x8*)&sA[(wm + mi * 16 + lr) * 32 + quad * 8];
#pragma unroll
        for (int ni = 0; ni < 4; ++ni)
            bfr[ni] = *(const bf16x8*)&sB[(wn + ni * 16 + lr) * 32 + quad * 8];
#pragma unroll
        for (int mi = 0; mi < 4; ++mi)
#pragma unroll
            for (int ni = 0; ni < 4; ++ni)
                acc[mi][ni] = __builtin_amdgcn_mfma_f32_16x16x32_bf16(bfr[ni], af[mi], acc[mi][ni], 0, 0, 0);
        __syncthreads();
    }

    // epilogue: row = m0+wm+mi*16+lr, cols = n0+wn+ni*16+quad*4 .. +3 (plain stores; L2 merges)
#pragma unroll
    for (int mi = 0; mi < 4; ++mi) {
        int row = m0 + wm + mi * 16 + lr;
#pragma unroll
        for (int ni = 0; ni < 4; ++ni) {
            int col = n0 + wn + ni * 16 + quad * 4;
            size_t idx = (size_t)row * N + col;
            f32x4 v = acc[mi][ni];
            if (bias) {
                const float4 b4 = *(const float4*)&bias[col];
                v[0] += b4.x; v[1] += b4.y; v[2] += b4.z; v[3] += b4.w;
            }
            if (act == 1) {
#pragma unroll
                for (int e = 0; e < 4; ++e) {
                    // tanh-approx gelu (max dev ~3e-4 vs exact; vanishes through next GEMM)
                    float xv = v[e];
                    float u = 0.7978845608f * (xv + 0.044715f * xv * xv * xv);
                    float ex = __expf(2.f * u);
                    float th = (ex - 1.f) / (ex + 1.f);
                    v[e] = 0.5f * xv * (1.f + th);
                }
            }
            if (add) {
                const float4 a4 = *(const float4*)&add[idx];
                v[0] += a4.x; v[1] += a4.y; v[2] += a4.z; v[3] += a4.w;
            }
            if (outH) {
                union { __hip_bfloat16 h[4]; int2 i2; } u;
                u.h[0] = __float2bfloat16(v[0]);
                u.h[1] = __float2bfloat16(v[1]);
                u.h[2] = __float2bfloat16(v[2]);
                u.h[3] = __float2bfloat16(v[3]);
                *(int2*)&outH[idx] = u.i2;
            } else {
                *(float4*)&outF[idx] = make_float4(v[0], v[1], v[2], v[3]);
            }
        }
    }
}

extern "C" void kernel_launch(void* const* d_in, const int* in_sizes, int n_in,
                              void* d_out, int out_size, void* d_ws, size_t ws_size,
                              hipStream_t stream) {
    const float* x = (const float*)d_in[0];
    const float* gamma1 = (const float*)d_in[1];
    const float* beta1 = (const float*)d_in[2];
    const float* dwc_w = (const float*)d_in[3];
    const float* dwc_b = (const float*)d_in[4];
    const float* gru1_w = (const float*)d_in[5];
    const float* gru1_o = (const float*)d_in[6];
    const float* gru2_w = (const float*)d_in[7];
    const float* gru2_o = (const float*)d_in[8];
    const float* gamma2 = (const float*)d_in[9];
    const float* beta2 = (const float*)d_in[10];
    const float* p1_w = (const float*)d_in[11];
    const float* p1_b = (const float*)d_in[12];
    const float* p2_w = (const float*)d_in[13];
    const float* p2_b = (const float*)d_in[14];
    float* out = (float*)d_out;

    char* ws = (char*)d_ws;
    size_t off = 0;
    auto alloc = [&](size_t b) {
        char* p = ws + off;
        off += (b + 255) & ~(size_t)255;
        return p;
    };
    const size_t M = M_ROWS;
    // ws total ~188 MB
    __hip_bfloat16* hg = (__hip_bfloat16*)alloc(M * 2 * DI * 2);    // 100.7 MB; h2 in-place; later t1
    __hip_bfloat16* hbuf = (__hip_bfloat16*)alloc(M * DI * 2);      // 50.3 MB: LN1-bf16 out, then h1
    __hip_bfloat16* xs = (__hip_bfloat16*)alloc(M * DIM * 2);       // 25.2 MB; later yn
    float* summ = (float*)alloc((size_t)2 * CHUNKS * NB * DI * 4);  // 6.3 MB
    __hip_bfloat16* w1T = (__hip_bfloat16*)alloc((size_t)DIM * 2 * DI * 2);
    __hip_bfloat16* w2T = (__hip_bfloat16*)alloc((size_t)DIM * 2 * DI * 2);
    __hip_bfloat16* ocT = (__hip_bfloat16*)alloc((size_t)DIM * 2 * DI * 2);  // 384 x 1536 = [o1;o2]^T
    __hip_bfloat16* p1T = (__hip_bfloat16*)alloc((size_t)DIM * MLP_DIM * 2);
    __hip_bfloat16* p2T = (__hip_bfloat16*)alloc((size_t)MLP_DIM * DIM * 2);
    __hip_bfloat16* xnb = hbuf;           // LN1 out (bf16); dead after dwconv, before scan1
    float* y = (float*)d_out;             // post-GRU residual; same-idx RMW only
    __hip_bfloat16* yn = xs;              // LN2 out; xs dead after GRU2 input GEMM
    __hip_bfloat16* t1 = hg;              // MLP hidden; hg dead after scan2

    auto tgrid = [](int n) { return dim3((n + 255) / 256); };
    transpose_bf16_kernel<<<tgrid(DIM * 2 * DI), 256, 0, stream>>>(gru1_w, w1T, DIM, 2 * DI, DIM, 0);
    transpose_bf16_kernel<<<tgrid(DIM * 2 * DI), 256, 0, stream>>>(gru2_w, w2T, DIM, 2 * DI, DIM, 0);
    transpose_bf16_kernel<<<tgrid(DI * DIM), 256, 0, stream>>>(gru1_o, ocT, DI, DIM, 2 * DI, 0);
    transpose_bf16_kernel<<<tgrid(DI * DIM), 256, 0, stream>>>(gru2_o, ocT, DI, DIM, 2 * DI, DI);
    transpose_bf16_kernel<<<tgrid(DIM * MLP_DIM), 256, 0, stream>>>(p1_w, p1T, DIM, MLP_DIM, DIM, 0);
    transpose_bf16_kernel<<<tgrid(MLP_DIM * DIM), 256, 0, stream>>>(p2_w, p2T, MLP_DIM, DIM, MLP_DIM, 0);

    ln_kernel<__hip_bfloat16><<<dim3(M / 4), 256, 0, stream>>>(x, gamma1, beta1, xnb);
    dwconv_kernel<<<dim3((M * DIM) / 256), 256, 0, stream>>>(xnb, dwc_w, dwc_b, xs);

    const int scan_blocks = NB * CHUNKS * DI / 256;  // 3072
    // GRU1: hg = xs @ w1; scan fwd -> h1 (hbuf, stride DI)
    gemm_bt<<<dim3(2 * DI / 128, M / 128), 256, 0, stream>>>(xs, DIM, xs, DIM, DIM, w1T, M, 2 * DI, DIM,
                                                             hg, nullptr, nullptr, nullptr, 0);
    scan_part1<<<dim3(scan_blocks), 256, 0, stream>>>(hg, summ, 0);
    scan_part2<<<dim3(scan_blocks), 256, 0, stream>>>(hg, summ, hbuf, 0, DI);
    // GRU2: hg = xs @ w2; scan bwd -> h2 in-place into hg[:, 0:DI] (stride 2*DI)
    gemm_bt<<<dim3(2 * DI / 128, M / 128), 256, 0, stream>>>(xs, DIM, xs, DIM, DIM, w2T, M, 2 * DI, DIM,
                                                             hg, nullptr, nullptr, nullptr, 0);
    scan_part1<<<dim3(scan_blocks), 256, 0, stream>>>(hg, summ, 1);
    scan_part2<<<dim3(scan_blocks), 256, 0, stream>>>(hg, summ, hg, 1, 2 * DI);

    // merged GRU out: y = [h1 | h2] @ [o1;o2] + x   (K=1536)
    gemm_bt<<<dim3(DIM / 128, M / 128), 256, 0, stream>>>(hbuf, DI, hg, 2 * DI, DI, ocT, M, DIM, 2 * DI,
                                                          nullptr, y, nullptr, x, 0);

    // LN2 + MLP
    ln_kernel<__hip_bfloat16><<<dim3(M / 4), 256, 0, stream>>>(y, gamma2, beta2, yn);
    gemm_bt<<<dim3(MLP_DIM / 128, M / 128), 256, 0, stream>>>(yn, DIM, yn, DIM, DIM, p1T, M, MLP_DIM, DIM,
                                                              t1, nullptr, p1_b, nullptr, 1);
    gemm_bt<<<dim3(DIM / 128, M / 128), 256, 0, stream>>>(t1, MLP_DIM, t1, MLP_DIM, MLP_DIM, p2T, M, DIM, MLP_DIM,
                                                          nullptr, out, p2_b, y, 0);
}